// Round 7
// baseline (648.608 us; speedup 1.0000x reference)
//
#include <hip/hip_runtime.h>
#include <math.h>

#define TOKS 8192
#define HD 1024
#define ID 2048
#define NE 8

typedef __bf16 bf16_t;
typedef __bf16 bf16x8 __attribute__((ext_vector_type(8)));
typedef float f32x4 __attribute__((ext_vector_type(4)));

// async global->LDS, 16 bytes per lane. LDS dest: wave-uniform base + lane*16.
#define GLOAD(gp, lp)                                                \
  __builtin_amdgcn_global_load_lds(                                  \
      (const __attribute__((address_space(1))) void*)(gp),           \
      (__attribute__((address_space(3))) void*)(lp), 16, 0, 0)

// ---------------- workspace layout (bytes) ----------------
#define WS_COUNTS 0
#define WS_OFFSETS 32
#define WS_BTOK 128
#define WS_BW (128 + 65536)
#define WS_TE (128 + 2 * 65536)
#define WS_TW (128 + 3 * 65536)
#define WS_WL 263168ull
#define WS_BLKC 266240ull                     // blk_cnt  [64][8] int
#define WS_BLKB 270336ull                     // blk_base [64][8] int
#define WS_XB 524288ull                       // bf16 x  [8192][1024]  = 16.78 MB
#define WS_H1 (WS_XB + 16777216ull)           // bf16 h1 [16384][2048] = 67.1 MB
#define WS_WT (WS_H1 + 67108864ull)           // bf16 WT (W1T then W2T) = 33.55 MB

#define MAXWL 80   // multiple of 8: (y*80+widx)%8 == widx%8 -> same-widx n-slices
                   // co-locate on one XCD (A panel L2 reuse)
#define BM 256     // m-tile (rows of token bucket)

// ---------------- zero out (hipMemsetAsync is NOT graph-capturable) ----
__global__ void zero_kernel(float* __restrict__ out) {
  const int i = (blockIdx.x * 256 + threadIdx.x) * 4;
  *(float4*)(out + i) = make_float4(0.f, 0.f, 0.f, 0.f);
}

// ---------------- x -> bf16 convert: pure streaming ----
__global__ void convert_kernel(const float* __restrict__ x, bf16_t* __restrict__ xb) {
  const size_t i = ((size_t)blockIdx.x * 256 + threadIdx.x) * 8;
  const float4 a = *(const float4*)(x + i);
  const float4 b = *(const float4*)(x + i + 4);
  bf16_t o[8] = {(bf16_t)a.x, (bf16_t)a.y, (bf16_t)a.z, (bf16_t)a.w,
                 (bf16_t)b.x, (bf16_t)b.y, (bf16_t)b.z, (bf16_t)b.w};
  *(uint4*)(xb + i) = *(uint4*)o;
}

// ---------------- gating: top-2 + weights, no atomics (r5 verified) ----
__global__ __launch_bounds__(256) void gate_kernel(const float* __restrict__ x,
                                                   const float* __restrict__ Wg,
                                                   int* __restrict__ tok_e,
                                                   float* __restrict__ tok_w) {
  __shared__ float WgT[NE][HD];  // 32 KB
  const int tid = threadIdx.x;
#pragma unroll
  for (int i = 0; i < NE * HD / 256; ++i) {
    const int idx = i * 256 + tid;
    WgT[idx & 7][idx >> 3] = Wg[idx];
  }
  __syncthreads();
  const int wv = tid >> 6;
  const int lane = tid & 63;
#pragma unroll
  for (int s = 0; s < 2; ++s) {
    const int t = blockIdx.x * 8 + wv * 2 + s;
    const float* xrow = x + (size_t)t * HD;
    float acc[NE];
#pragma unroll
    for (int e = 0; e < NE; ++e) acc[e] = 0.f;
#pragma unroll
    for (int i = 0; i < 16; ++i) {
      const int h = i * 64 + lane;
      const float xv = xrow[h];
#pragma unroll
      for (int e = 0; e < NE; ++e) acc[e] += xv * WgT[e][h];
    }
#pragma unroll
    for (int off = 32; off >= 1; off >>= 1) {
#pragma unroll
      for (int e = 0; e < NE; ++e) acc[e] += __shfl_xor(acc[e], off);
    }
    if (lane == 0) {
      int i1 = 0;
      float l1 = acc[0];
#pragma unroll
      for (int e = 1; e < NE; ++e)
        if (acc[e] > l1) { l1 = acc[e]; i1 = e; }
      int i2 = -1;
      float l2 = -3.4e38f;
#pragma unroll
      for (int e = 0; e < NE; ++e)
        if (e != i1 && acc[e] > l2) { l2 = acc[e]; i2 = e; }
      const float q = expf(l2 - l1);
      const float w1 = 1.f / (1.f + q);
      tok_e[2 * t] = i1;
      tok_e[2 * t + 1] = i2;
      tok_w[2 * t] = w1;
      tok_w[2 * t + 1] = q * w1;
    }
  }
}

// ---------------- histogram: per-block per-expert counts via wave ballots ----
__global__ __launch_bounds__(256) void hist_kernel(const int* __restrict__ tok_e,
                                                   int* __restrict__ blk_cnt) {
  __shared__ int wcnt[4][NE];
  const int tid = threadIdx.x;
  const int idx = blockIdx.x * 256 + tid;
  const int e = tok_e[idx];
  const int w = tid >> 6;
  const int lane = tid & 63;
#pragma unroll
  for (int e0 = 0; e0 < NE; ++e0) {
    const unsigned long long m = __ballot(e == e0);
    if (lane == 0) wcnt[w][e0] = __popcll(m);
  }
  __syncthreads();
  if (tid < NE)
    blk_cnt[blockIdx.x * NE + tid] =
        wcnt[0][tid] + wcnt[1][tid] + wcnt[2][tid] + wcnt[3][tid];
}

// ---------------- scan: one wave; 64-wide shfl prefix-sum per expert ----
__global__ void scan_kernel(const int* __restrict__ blk_cnt, int* __restrict__ counts,
                            int* __restrict__ offsets, int* __restrict__ blk_base,
                            int* __restrict__ wl_e, int* __restrict__ wl_m,
                            int* __restrict__ n_work) {
  const int b = threadIdx.x;  // 0..63, one per scatter block
  int c[NE], pre[NE], tot[NE];
#pragma unroll
  for (int e = 0; e < NE; ++e) c[e] = blk_cnt[b * NE + e];
#pragma unroll
  for (int e = 0; e < NE; ++e) {
    int v = c[e];
#pragma unroll
    for (int off = 1; off < 64; off <<= 1) {
      const int u = __shfl_up(v, off);
      if (b >= off) v += u;
    }
    pre[e] = v - c[e];          // exclusive prefix over blocks
    tot[e] = __shfl(v, 63);     // expert total
  }
  int off_[NE];
  int s = 0;
#pragma unroll
  for (int e = 0; e < NE; ++e) {
    off_[e] = s;
    s += tot[e];
  }
#pragma unroll
  for (int e = 0; e < NE; ++e) blk_base[b * NE + e] = off_[e] + pre[e];
  if (b == 0) {
    int idx = 0;
    for (int e = 0; e < NE; ++e) {
      counts[e] = tot[e];
      offsets[e] = off_[e];
      for (int m = 0; m < tot[e] && idx < MAXWL; m += BM) {
        wl_e[idx] = e;
        wl_m[idx] = m;
        ++idx;
      }
    }
    *n_work = idx;
  }
}

// ---------------- scatter: position = blk_base + wave prefix + ballot rank ----
__global__ __launch_bounds__(256) void scatter_kernel(const int* __restrict__ tok_e,
                                                      const float* __restrict__ tok_w,
                                                      const int* __restrict__ blk_base,
                                                      int* __restrict__ bucket_tok,
                                                      float* __restrict__ bucket_w) {
  __shared__ int wcnt[4][NE];
  const int tid = threadIdx.x;
  const int idx = blockIdx.x * 256 + tid;
  const int e = tok_e[idx];
  const int w = tid >> 6;
  const int lane = tid & 63;
  unsigned long long mym = 0;
#pragma unroll
  for (int e0 = 0; e0 < NE; ++e0) {
    const unsigned long long m = __ballot(e == e0);
    if (lane == 0) wcnt[w][e0] = __popcll(m);
    if (e0 == e) mym = m;
  }
  __syncthreads();
  int base = blk_base[blockIdx.x * NE + e];
  for (int w2 = 0; w2 < w; ++w2) base += wcnt[w2][e];
  const int rank = __popcll(mym & ((1ull << lane) - 1ull));
  const int pos = base + rank;
  bucket_tok[pos] = idx >> 1;
  bucket_w[pos] = tok_w[idx];
}

// ---------------- transpose+convert: src [E][K][N] f32 -> dst [E][N][K] bf16 ----
__global__ __launch_bounds__(256) void transpose_convert_kernel(const float* __restrict__ src,
                                                                bf16_t* __restrict__ dst, int K,
                                                                int N) {
  __shared__ float tile[64][65];
  const int e = blockIdx.z;
  const int k0 = blockIdx.x * 64;
  const int n0 = blockIdx.y * 64;
  const float* s = src + (size_t)e * K * N;
  bf16_t* d = dst + (size_t)e * K * N;
  const int t = threadIdx.x;
  const int c = t & 63;
  const int r4 = t >> 6;
#pragma unroll
  for (int p = 0; p < 16; ++p) {
    const int r = p * 4 + r4;
    tile[r][c] = s[(size_t)(k0 + r) * N + n0 + c];
  }
  __syncthreads();
  const int kc = t & 7;
  const int nb = t >> 3;
#pragma unroll
  for (int p = 0; p < 2; ++p) {
    const int n = p * 32 + nb;
    bf16_t o[8];
#pragma unroll
    for (int j = 0; j < 8; ++j) o[j] = (bf16_t)tile[kc * 8 + j][n];
    *(uint4*)(d + (size_t)(n0 + n) * K + k0 + kc * 8) = *(uint4*)o;
  }
}

// ---------------- expert GEMMs: 256x128 tile, BK=64, 8 waves, 2ph (m248 config) ----
// BK=64 (128B-contiguous k-slices; kills the 2x line overfetch BK=32 caused),
// 8 waves (4 wm x 2 wn, wave tile 64x64, acc[4][4] -- epilogue math unchanged
// from verified rounds), ONE __syncthreads per K-step (2ph recipe), LDS 96KB
// dbuf -> 1 block/CU.
// Swizzle (rule 21, both sides, 8 slots/row): GLOAD source chunk
// kch=((lane&7)^(srow&7))*8; phys slot s of row r holds logical chunk s^(r&7);
// read slot = (kk*4+quad)^(lrow&7) with row&7==lrow&7 (band offsets are
// multiples of 8). 16-lane read groups hit 8 distinct slots x 2 row-parities
// = 2-way on banks = free (m136).

__global__ __launch_bounds__(512, 1) void gemm1_kernel(
    const bf16_t* __restrict__ xb, const bf16_t* __restrict__ W1T, const float* __restrict__ b1,
    const int* __restrict__ counts, const int* __restrict__ offsets,
    const int* __restrict__ bucket_tok, const int* __restrict__ wl_e,
    const int* __restrict__ wl_m, const int* __restrict__ n_work, bf16_t* __restrict__ h1) {
  const int widx = blockIdx.x;
  if (widx >= *n_work) return;
  const int e = wl_e[widx];
  const int m_base = wl_m[widx];
  const int n_e = counts[e];
  const int n_base = blockIdx.y * 128;
  const int off = offsets[e];

  __shared__ bf16_t As[2][256 * 64];  // 32 KB each
  __shared__ bf16_t Bs[2][128 * 64];  // 16 KB each

  const int tid = threadIdx.x;
  const int w = tid >> 6;        // 0..7
  const int lane = tid & 63;
  const int quad = lane >> 4;    // 0..3
  const int lrow = lane & 15;
  const int wm = w >> 1;         // 0..3 : 64-row band
  const int wn = w & 1;          // 0..1 : 64-col band

  // staging geometry: 8 rows / GLOAD (8 lanes x 16B = 128B per row)
  const int srow = lane >> 3;                       // 0..7
  const int kch = (((lane & 7) ^ (srow & 7)) * 8);  // pre-swizzled source chunk
  // A: wave stages rows w*32 .. w*32+31 (4 GLOADs)
  const bf16_t* ga[4];
#pragma unroll
  for (int g = 0; g < 4; ++g) {
    int r = m_base + w * 32 + g * 8 + srow;
    if (r >= n_e) r = n_e - 1;
    ga[g] = xb + (size_t)bucket_tok[off + r] * HD + kch;
  }
  // B: wave stages rows w*16 .. w*16+15 (2 GLOADs)
  const bf16_t* gb[2];
#pragma unroll
  for (int g = 0; g < 2; ++g)
    gb[g] = W1T + ((size_t)e * ID + n_base + w * 16 + g * 8 + srow) * HD + kch;
  int aofs[4], bofs[2];
#pragma unroll
  for (int g = 0; g < 4; ++g) aofs[g] = (w * 32 + g * 8) * 64 + lane * 8;
#pragma unroll
  for (int g = 0; g < 2; ++g) bofs[g] = (w * 16 + g * 8) * 64 + lane * 8;

  f32x4 acc[4][4];
#pragma unroll
  for (int mt = 0; mt < 4; ++mt)
#pragma unroll
    for (int nt = 0; nt < 4; ++nt)
#pragma unroll
      for (int r = 0; r < 4; ++r) acc[mt][nt][r] = 0.f;

  // read-side swizzled slot offsets (elements) for kk=0,1
  const int s0 = ((0 * 4 + quad) ^ (lrow & 7)) * 8;
  const int s1 = ((1 * 4 + quad) ^ (lrow & 7)) * 8;

  // prologue: stage tile 0 into buffer 0
#pragma unroll
  for (int g = 0; g < 4; ++g) GLOAD(ga[g], &As[0][aofs[g]]);
#pragma unroll
  for (int g = 0; g < 2; ++g) GLOAD(gb[g], &Bs[0][bofs[g]]);
  __syncthreads();

#define NT1 (HD / 64)
  for (int kt = 0; kt < NT1; ++kt) {
    const int cur = kt & 1;
    if (kt + 1 < NT1) {  // stage next tile first (HBM latency hides under MFMA)
      const int nxt = cur ^ 1;
      const size_t ko = (size_t)(kt + 1) * 64;
#pragma unroll
      for (int g = 0; g < 4; ++g) GLOAD(ga[g] + ko, &As[nxt][aofs[g]]);
#pragma unroll
      for (int g = 0; g < 2; ++g) GLOAD(gb[g] + ko, &Bs[nxt][bofs[g]]);
    }
#pragma unroll
    for (int kk = 0; kk < 2; ++kk) {
      const int sl = kk ? s1 : s0;
      bf16x8 af[4], bfr[4];
#pragma unroll
      for (int i = 0; i < 4; ++i) {
        af[i] = *(const bf16x8*)(&As[cur][(wm * 64 + i * 16 + lrow) * 64 + sl]);
        bfr[i] = *(const bf16x8*)(&Bs[cur][(wn * 64 + i * 16 + lrow) * 64 + sl]);
      }
#pragma unroll
      for (int mt = 0; mt < 4; ++mt)
#pragma unroll
        for (int nt = 0; nt < 4; ++nt)
          acc[mt][nt] =
              __builtin_amdgcn_mfma_f32_16x16x32_bf16(af[mt], bfr[nt], acc[mt][nt], 0, 0, 0);
    }
    __syncthreads();  // drains vmcnt(0)+lgkmcnt(0): next tile staged, reads done
  }

#pragma unroll
  for (int mt = 0; mt < 4; ++mt) {
#pragma unroll
    for (int r = 0; r < 4; ++r) {
      const int gm = m_base + wm * 64 + mt * 16 + quad * 4 + r;
      if (gm < n_e) {
        bf16_t* orow = h1 + (size_t)(off + gm) * ID;
#pragma unroll
        for (int nt = 0; nt < 4; ++nt) {
          const int gi = n_base + wn * 64 + nt * 16 + lrow;
          float v = acc[mt][nt][r] + b1[e * ID + gi];
          v = 0.5f * v * (1.f + erff(v * 0.70710678118654752f));  // exact-erf GELU
          orow[gi] = (bf16_t)v;
        }
      }
    }
  }
}

__global__ __launch_bounds__(512, 1) void gemm2_kernel(
    const bf16_t* __restrict__ h1, const bf16_t* __restrict__ W2T, const float* __restrict__ b2,
    const int* __restrict__ counts, const int* __restrict__ offsets,
    const int* __restrict__ bucket_tok, const float* __restrict__ bucket_w,
    const int* __restrict__ wl_e, const int* __restrict__ wl_m, const int* __restrict__ n_work,
    float* __restrict__ out) {
  const int widx = blockIdx.x;
  if (widx >= *n_work) return;
  const int e = wl_e[widx];
  const int m_base = wl_m[widx];
  const int n_e = counts[e];
  const int n_base = blockIdx.y * 128;
  const int off = offsets[e];

  __shared__ bf16_t As[2][256 * 64];
  __shared__ bf16_t Bs[2][128 * 64];

  const int tid = threadIdx.x;
  const int w = tid >> 6;
  const int lane = tid & 63;
  const int quad = lane >> 4;
  const int lrow = lane & 15;
  const int wm = w >> 1;
  const int wn = w & 1;

  const int srow = lane >> 3;
  const int kch = (((lane & 7) ^ (srow & 7)) * 8);
  const bf16_t* ga[4];
#pragma unroll
  for (int g = 0; g < 4; ++g) {
    int r = m_base + w * 32 + g * 8 + srow;
    if (r >= n_e) r = n_e - 1;
    ga[g] = h1 + (size_t)(off + r) * ID + kch;  // A rows are bucket-contiguous here
  }
  const bf16_t* gb[2];
#pragma unroll
  for (int g = 0; g < 2; ++g)
    gb[g] = W2T + ((size_t)e * HD + n_base + w * 16 + g * 8 + srow) * ID + kch;
  int aofs[4], bofs[2];
#pragma unroll
  for (int g = 0; g < 4; ++g) aofs[g] = (w * 32 + g * 8) * 64 + lane * 8;
#pragma unroll
  for (int g = 0; g < 2; ++g) bofs[g] = (w * 16 + g * 8) * 64 + lane * 8;

  f32x4 acc[4][4];
#pragma unroll
  for (int mt = 0; mt < 4; ++mt)
#pragma unroll
    for (int nt = 0; nt < 4; ++nt)
#pragma unroll
      for (int r = 0; r < 4; ++r) acc[mt][nt][r] = 0.f;

  const int s0 = ((0 * 4 + quad) ^ (lrow & 7)) * 8;
  const int s1 = ((1 * 4 + quad) ^ (lrow & 7)) * 8;

#pragma unroll
  for (int g = 0; g < 4; ++g) GLOAD(ga[g], &As[0][aofs[g]]);
#pragma unroll
  for (int g = 0; g < 2; ++g) GLOAD(gb[g], &Bs[0][bofs[g]]);
  __syncthreads();

#define NT2 (ID / 64)
  for (int kt = 0; kt < NT2; ++kt) {
    const int cur = kt & 1;
    if (kt + 1 < NT2) {
      const int nxt = cur ^ 1;
      const size_t ko = (size_t)(kt + 1) * 64;
#pragma unroll
      for (int g = 0; g < 4; ++g) GLOAD(ga[g] + ko, &As[nxt][aofs[g]]);
#pragma unroll
      for (int g = 0; g < 2; ++g) GLOAD(gb[g] + ko, &Bs[nxt][bofs[g]]);
    }
#pragma unroll
    for (int kk = 0; kk < 2; ++kk) {
      const int sl = kk ? s1 : s0;
      bf16x8 af[4], bfr[4];
#pragma unroll
      for (int i = 0; i < 4; ++i) {
        af[i] = *(const bf16x8*)(&As[cur][(wm * 64 + i * 16 + lrow) * 64 + sl]);
        bfr[i] = *(const bf16x8*)(&Bs[cur][(wn * 64 + i * 16 + lrow) * 64 + sl]);
      }
#pragma unroll
      for (int mt = 0; mt < 4; ++mt)
#pragma unroll
        for (int nt = 0; nt < 4; ++nt)
          acc[mt][nt] =
              __builtin_amdgcn_mfma_f32_16x16x32_bf16(af[mt], bfr[nt], acc[mt][nt], 0, 0, 0);
    }
    __syncthreads();
  }

#pragma unroll
  for (int mt = 0; mt < 4; ++mt) {
#pragma unroll
    for (int r = 0; r < 4; ++r) {
      const int gm = m_base + wm * 64 + mt * 16 + quad * 4 + r;
      if (gm < n_e) {
        const int pos = off + gm;
        const int tokid = bucket_tok[pos];
        const float wgt = bucket_w[pos];
        float* orow = out + (size_t)tokid * HD;
#pragma unroll
        for (int nt = 0; nt < 4; ++nt) {
          const int gh = n_base + wn * 64 + nt * 16 + lrow;
          float v = acc[mt][nt][r] + b2[e * HD + gh];
          atomicAdd(orow + gh, wgt * v);
        }
      }
    }
  }
}

extern "C" void kernel_launch(void* const* d_in, const int* in_sizes, int n_in,
                              void* d_out, int out_size, void* d_ws, size_t ws_size,
                              hipStream_t stream) {
  const float* x = (const float*)d_in[0];
  const float* Wg = (const float*)d_in[1];
  const float* W1 = (const float*)d_in[2];
  const float* b1 = (const float*)d_in[3];
  const float* W2 = (const float*)d_in[4];
  const float* b2 = (const float*)d_in[5];
  float* out = (float*)d_out;
  char* ws = (char*)d_ws;

  int* counts = (int*)(ws + WS_COUNTS);
  int* offsets = (int*)(ws + WS_OFFSETS);
  int* bucket_tok = (int*)(ws + WS_BTOK);
  float* bucket_w = (float*)(ws + WS_BW);
  int* tok_e = (int*)(ws + WS_TE);
  float* tok_w = (float*)(ws + WS_TW);
  int* wl_e = (int*)(ws + WS_WL);
  int* wl_m = wl_e + MAXWL;
  int* n_work = wl_m + MAXWL;
  int* blk_cnt = (int*)(ws + WS_BLKC);
  int* blk_base = (int*)(ws + WS_BLKB);
  bf16_t* xb = (bf16_t*)(ws + WS_XB);
  bf16_t* h1 = (bf16_t*)(ws + WS_H1);
  bf16_t* WT = (bf16_t*)(ws + WS_WT);

  zero_kernel<<<(TOKS * HD / 4) / 256, 256, 0, stream>>>(out);
  convert_kernel<<<TOKS * HD / (256 * 8), 256, 0, stream>>>(x, xb);
  gate_kernel<<<TOKS / 8, 256, 0, stream>>>(x, Wg, tok_e, tok_w);
  hist_kernel<<<TOKS * 2 / 256, 256, 0, stream>>>(tok_e, blk_cnt);
  scan_kernel<<<1, 64, 0, stream>>>(blk_cnt, counts, offsets, blk_base, wl_e, wl_m, n_work);
  scatter_kernel<<<TOKS * 2 / 256, 256, 0, stream>>>(tok_e, tok_w, blk_base, bucket_tok,
                                                     bucket_w);
  transpose_convert_kernel<<<dim3(HD / 64, ID / 64, NE), 256, 0, stream>>>(W1, WT, HD, ID);
  gemm1_kernel<<<dim3(MAXWL, ID / 128), 512, 0, stream>>>(xb, WT, b1, counts, offsets, bucket_tok,
                                                          wl_e, wl_m, n_work, h1);
  transpose_convert_kernel<<<dim3(ID / 64, HD / 64, NE), 256, 0, stream>>>(W2, WT, ID, HD);
  gemm2_kernel<<<dim3(MAXWL, HD / 128), 512, 0, stream>>>(h1, WT, b2, counts, offsets,
                                                          bucket_tok, bucket_w, wl_e, wl_m,
                                                          n_work, out);
}

// Round 8
// 630.966 us; speedup vs baseline: 1.0280x; 1.0280x over previous
//
#include <hip/hip_runtime.h>
#include <math.h>

#define TOKS 8192
#define HD 1024
#define ID 2048
#define NE 8

typedef __bf16 bf16_t;
typedef __bf16 bf16x8 __attribute__((ext_vector_type(8)));
typedef float f32x4 __attribute__((ext_vector_type(4)));

// async global->LDS, 16 bytes per lane. LDS dest: wave-uniform base + lane*16.
#define GLOAD(gp, lp)                                                \
  __builtin_amdgcn_global_load_lds(                                  \
      (const __attribute__((address_space(1))) void*)(gp),           \
      (__attribute__((address_space(3))) void*)(lp), 16, 0, 0)

// ---------------- workspace layout (bytes) ----------------
#define WS_COUNTS 0
#define WS_OFFSETS 32
#define WS_BTOK 128
#define WS_BW (128 + 65536)
#define WS_TE (128 + 2 * 65536)
#define WS_TW (128 + 3 * 65536)
#define WS_WL 263168ull
#define WS_BLKC 266240ull                     // blk_cnt  [64][8] int
#define WS_BLKB 270336ull                     // blk_base [64][8] int
#define WS_XB 524288ull                       // bf16 x  [8192][1024]  = 16.78 MB
#define WS_H1 (WS_XB + 16777216ull)           // bf16 h1 [16384][2048] = 67.1 MB
#define WS_WT (WS_H1 + 67108864ull)           // bf16 WT (W1T then W2T) = 33.55 MB

#define MAXWL 80
#define BM 256     // m-tile (rows of token bucket)

// ---------------- zero out (hipMemsetAsync is NOT graph-capturable) ----
__global__ void zero_kernel(float* __restrict__ out) {
  const int i = (blockIdx.x * 256 + threadIdx.x) * 4;
  *(float4*)(out + i) = make_float4(0.f, 0.f, 0.f, 0.f);
}

// ---------------- x -> bf16 convert: pure streaming ----
__global__ void convert_kernel(const float* __restrict__ x, bf16_t* __restrict__ xb) {
  const size_t i = ((size_t)blockIdx.x * 256 + threadIdx.x) * 8;
  const float4 a = *(const float4*)(x + i);
  const float4 b = *(const float4*)(x + i + 4);
  bf16_t o[8] = {(bf16_t)a.x, (bf16_t)a.y, (bf16_t)a.z, (bf16_t)a.w,
                 (bf16_t)b.x, (bf16_t)b.y, (bf16_t)b.z, (bf16_t)b.w};
  *(uint4*)(xb + i) = *(uint4*)o;
}

// ---------------- gating: top-2 + weights, no atomics (r5 verified) ----
__global__ __launch_bounds__(256) void gate_kernel(const float* __restrict__ x,
                                                   const float* __restrict__ Wg,
                                                   int* __restrict__ tok_e,
                                                   float* __restrict__ tok_w) {
  __shared__ float WgT[NE][HD];  // 32 KB
  const int tid = threadIdx.x;
#pragma unroll
  for (int i = 0; i < NE * HD / 256; ++i) {
    const int idx = i * 256 + tid;
    WgT[idx & 7][idx >> 3] = Wg[idx];
  }
  __syncthreads();
  const int wv = tid >> 6;
  const int lane = tid & 63;
#pragma unroll
  for (int s = 0; s < 2; ++s) {
    const int t = blockIdx.x * 8 + wv * 2 + s;
    const float* xrow = x + (size_t)t * HD;
    float acc[NE];
#pragma unroll
    for (int e = 0; e < NE; ++e) acc[e] = 0.f;
#pragma unroll
    for (int i = 0; i < 16; ++i) {
      const int h = i * 64 + lane;
      const float xv = xrow[h];
#pragma unroll
      for (int e = 0; e < NE; ++e) acc[e] += xv * WgT[e][h];
    }
#pragma unroll
    for (int off = 32; off >= 1; off >>= 1) {
#pragma unroll
      for (int e = 0; e < NE; ++e) acc[e] += __shfl_xor(acc[e], off);
    }
    if (lane == 0) {
      int i1 = 0;
      float l1 = acc[0];
#pragma unroll
      for (int e = 1; e < NE; ++e)
        if (acc[e] > l1) { l1 = acc[e]; i1 = e; }
      int i2 = -1;
      float l2 = -3.4e38f;
#pragma unroll
      for (int e = 0; e < NE; ++e)
        if (e != i1 && acc[e] > l2) { l2 = acc[e]; i2 = e; }
      const float q = expf(l2 - l1);
      const float w1 = 1.f / (1.f + q);
      tok_e[2 * t] = i1;
      tok_e[2 * t + 1] = i2;
      tok_w[2 * t] = w1;
      tok_w[2 * t + 1] = q * w1;
    }
  }
}

// ---------------- histogram: per-block per-expert counts via wave ballots ----
__global__ __launch_bounds__(256) void hist_kernel(const int* __restrict__ tok_e,
                                                   int* __restrict__ blk_cnt) {
  __shared__ int wcnt[4][NE];
  const int tid = threadIdx.x;
  const int idx = blockIdx.x * 256 + tid;
  const int e = tok_e[idx];
  const int w = tid >> 6;
  const int lane = tid & 63;
#pragma unroll
  for (int e0 = 0; e0 < NE; ++e0) {
    const unsigned long long m = __ballot(e == e0);
    if (lane == 0) wcnt[w][e0] = __popcll(m);
  }
  __syncthreads();
  if (tid < NE)
    blk_cnt[blockIdx.x * NE + tid] =
        wcnt[0][tid] + wcnt[1][tid] + wcnt[2][tid] + wcnt[3][tid];
}

// ---------------- scan: one wave; 64-wide shfl prefix-sum per expert ----
__global__ void scan_kernel(const int* __restrict__ blk_cnt, int* __restrict__ counts,
                            int* __restrict__ offsets, int* __restrict__ blk_base,
                            int* __restrict__ wl_e, int* __restrict__ wl_m,
                            int* __restrict__ n_work) {
  const int b = threadIdx.x;  // 0..63, one per scatter block
  int c[NE], pre[NE], tot[NE];
#pragma unroll
  for (int e = 0; e < NE; ++e) c[e] = blk_cnt[b * NE + e];
#pragma unroll
  for (int e = 0; e < NE; ++e) {
    int v = c[e];
#pragma unroll
    for (int off = 1; off < 64; off <<= 1) {
      const int u = __shfl_up(v, off);
      if (b >= off) v += u;
    }
    pre[e] = v - c[e];          // exclusive prefix over blocks
    tot[e] = __shfl(v, 63);     // expert total
  }
  int off_[NE];
  int s = 0;
#pragma unroll
  for (int e = 0; e < NE; ++e) {
    off_[e] = s;
    s += tot[e];
  }
#pragma unroll
  for (int e = 0; e < NE; ++e) blk_base[b * NE + e] = off_[e] + pre[e];
  if (b == 0) {
    int idx = 0;
    for (int e = 0; e < NE; ++e) {
      counts[e] = tot[e];
      offsets[e] = off_[e];
      for (int m = 0; m < tot[e] && idx < MAXWL; m += BM) {
        wl_e[idx] = e;
        wl_m[idx] = m;
        ++idx;
      }
    }
    *n_work = idx;
  }
}

// ---------------- scatter: position = blk_base + wave prefix + ballot rank ----
__global__ __launch_bounds__(256) void scatter_kernel(const int* __restrict__ tok_e,
                                                      const float* __restrict__ tok_w,
                                                      const int* __restrict__ blk_base,
                                                      int* __restrict__ bucket_tok,
                                                      float* __restrict__ bucket_w) {
  __shared__ int wcnt[4][NE];
  const int tid = threadIdx.x;
  const int idx = blockIdx.x * 256 + tid;
  const int e = tok_e[idx];
  const int w = tid >> 6;
  const int lane = tid & 63;
  unsigned long long mym = 0;
#pragma unroll
  for (int e0 = 0; e0 < NE; ++e0) {
    const unsigned long long m = __ballot(e == e0);
    if (lane == 0) wcnt[w][e0] = __popcll(m);
    if (e0 == e) mym = m;
  }
  __syncthreads();
  int base = blk_base[blockIdx.x * NE + e];
  for (int w2 = 0; w2 < w; ++w2) base += wcnt[w2][e];
  const int rank = __popcll(mym & ((1ull << lane) - 1ull));
  const int pos = base + rank;
  bucket_tok[pos] = idx >> 1;
  bucket_w[pos] = tok_w[idx];
}

// ---------------- transpose+convert: src [E][K][N] f32 -> dst [E][N][K] bf16 ----
__global__ __launch_bounds__(256) void transpose_convert_kernel(const float* __restrict__ src,
                                                                bf16_t* __restrict__ dst, int K,
                                                                int N) {
  __shared__ float tile[64][65];
  const int e = blockIdx.z;
  const int k0 = blockIdx.x * 64;
  const int n0 = blockIdx.y * 64;
  const float* s = src + (size_t)e * K * N;
  bf16_t* d = dst + (size_t)e * K * N;
  const int t = threadIdx.x;
  const int c = t & 63;
  const int r4 = t >> 6;
#pragma unroll
  for (int p = 0; p < 16; ++p) {
    const int r = p * 4 + r4;
    tile[r][c] = s[(size_t)(k0 + r) * N + n0 + c];
  }
  __syncthreads();
  const int kc = t & 7;
  const int nb = t >> 3;
#pragma unroll
  for (int p = 0; p < 2; ++p) {
    const int n = p * 32 + nb;
    bf16_t o[8];
#pragma unroll
    for (int j = 0; j < 8; ++j) o[j] = (bf16_t)tile[kc * 8 + j][n];
    *(uint4*)(d + (size_t)(n0 + n) * K + k0 + kc * 8) = *(uint4*)o;
  }
}

// ---------------- expert GEMMs: 256x256 tile, BK=64, 8 waves (2Mx4N), 2ph ----
// r7 post-mortem: 256x128 gave up inter-block overlap (1 blk/CU) without
// enough per-barrier work (wave tile 64x64) -> 273 TF. The learn-loop's
// grouped-GEMM reference (m230-V0/m248-V0) at THIS config measured 655-682 TF:
// 256x256, 8 waves, wave tile 128x64, acc[8][4], BK=64, one sync per K-step.
// FLOP/LDS-read-byte = 44, FLOP/staged-byte = 128; per-CU LDS-port time ~=
// MFMA time (balanced). LDS 128 KB (2buf x (A 32K + B 32K)) -> 1 block/CU.
// Swizzle: verified r7 (refcheck pass + SQ_LDS_BANK_CONFLICT == 0): GLOAD
// source chunk kch=((lane&7)^(srow&7))*8; phys slot s of row r holds logical
// chunk s^(r&7); read slot ((kk*4+quad)^(lrow&7))*8, row&7==lrow&7 since all
// row-band offsets are multiples of 8.

__global__ __launch_bounds__(512, 1) void gemm1_kernel(
    const bf16_t* __restrict__ xb, const bf16_t* __restrict__ W1T, const float* __restrict__ b1,
    const int* __restrict__ counts, const int* __restrict__ offsets,
    const int* __restrict__ bucket_tok, const int* __restrict__ wl_e,
    const int* __restrict__ wl_m, const int* __restrict__ n_work, bf16_t* __restrict__ h1) {
  const int widx = blockIdx.x;
  if (widx >= *n_work) return;
  const int e = wl_e[widx];
  const int m_base = wl_m[widx];
  const int n_e = counts[e];
  const int n_base = blockIdx.y * 256;
  const int off = offsets[e];

  __shared__ bf16_t As[2][256 * 64];  // 32 KB each
  __shared__ bf16_t Bs[2][256 * 64];  // 32 KB each

  const int tid = threadIdx.x;
  const int w = tid >> 6;        // 0..7
  const int lane = tid & 63;
  const int quad = lane >> 4;    // 0..3
  const int lrow = lane & 15;
  const int wm = w >> 2;         // 0..1 : 128-row band
  const int wn = w & 3;          // 0..3 : 64-col band

  // staging: 8 rows / GLOAD (8 lanes x 16B = 128B per row); wave stages
  // A rows w*32..w*32+31 (4 GLOADs) and B rows w*32..w*32+31 (4 GLOADs)
  const int srow = lane >> 3;                       // 0..7
  const int kch = (((lane & 7) ^ (srow & 7)) * 8);  // pre-swizzled source chunk
  const bf16_t* ga[4];
#pragma unroll
  for (int g = 0; g < 4; ++g) {
    int r = m_base + w * 32 + g * 8 + srow;
    if (r >= n_e) r = n_e - 1;
    ga[g] = xb + (size_t)bucket_tok[off + r] * HD + kch;
  }
  const bf16_t* gb[4];
#pragma unroll
  for (int g = 0; g < 4; ++g)
    gb[g] = W1T + ((size_t)e * ID + n_base + w * 32 + g * 8 + srow) * HD + kch;
  int aofs[4], bofs[4];
#pragma unroll
  for (int g = 0; g < 4; ++g) {
    aofs[g] = (w * 32 + g * 8) * 64 + lane * 8;
    bofs[g] = (w * 32 + g * 8) * 64 + lane * 8;
  }

  f32x4 acc[8][4];
#pragma unroll
  for (int mt = 0; mt < 8; ++mt)
#pragma unroll
    for (int nt = 0; nt < 4; ++nt)
#pragma unroll
      for (int r = 0; r < 4; ++r) acc[mt][nt][r] = 0.f;

  const int s0 = ((0 * 4 + quad) ^ (lrow & 7)) * 8;
  const int s1 = ((1 * 4 + quad) ^ (lrow & 7)) * 8;

  // prologue: stage tile 0 into buffer 0
#pragma unroll
  for (int g = 0; g < 4; ++g) GLOAD(ga[g], &As[0][aofs[g]]);
#pragma unroll
  for (int g = 0; g < 4; ++g) GLOAD(gb[g], &Bs[0][bofs[g]]);
  __syncthreads();

#define NT1 (HD / 64)
  for (int kt = 0; kt < NT1; ++kt) {
    const int cur = kt & 1;
    if (kt + 1 < NT1) {  // stage next tile first (HBM latency hides under MFMA)
      const int nxt = cur ^ 1;
      const size_t ko = (size_t)(kt + 1) * 64;
#pragma unroll
      for (int g = 0; g < 4; ++g) GLOAD(ga[g] + ko, &As[nxt][aofs[g]]);
#pragma unroll
      for (int g = 0; g < 4; ++g) GLOAD(gb[g] + ko, &Bs[nxt][bofs[g]]);
    }
#pragma unroll
    for (int kk = 0; kk < 2; ++kk) {
      const int sl = kk ? s1 : s0;
      bf16x8 bfr[4];
#pragma unroll
      for (int i = 0; i < 4; ++i)
        bfr[i] = *(const bf16x8*)(&Bs[cur][(wn * 64 + i * 16 + lrow) * 64 + sl]);
#pragma unroll
      for (int mt = 0; mt < 8; ++mt) {
        const bf16x8 af = *(const bf16x8*)(&As[cur][(wm * 128 + mt * 16 + lrow) * 64 + sl]);
#pragma unroll
        for (int nt = 0; nt < 4; ++nt)
          acc[mt][nt] = __builtin_amdgcn_mfma_f32_16x16x32_bf16(af, bfr[nt], acc[mt][nt], 0, 0, 0);
      }
    }
    __syncthreads();  // drains vmcnt(0)+lgkmcnt(0): next tile staged, reads done
  }

#pragma unroll
  for (int mt = 0; mt < 8; ++mt) {
#pragma unroll
    for (int r = 0; r < 4; ++r) {
      const int gm = m_base + wm * 128 + mt * 16 + quad * 4 + r;
      if (gm < n_e) {
        bf16_t* orow = h1 + (size_t)(off + gm) * ID;
#pragma unroll
        for (int nt = 0; nt < 4; ++nt) {
          const int gi = n_base + wn * 64 + nt * 16 + lrow;
          float v = acc[mt][nt][r] + b1[e * ID + gi];
          v = 0.5f * v * (1.f + erff(v * 0.70710678118654752f));  // exact-erf GELU
          orow[gi] = (bf16_t)v;
        }
      }
    }
  }
}

__global__ __launch_bounds__(512, 1) void gemm2_kernel(
    const bf16_t* __restrict__ h1, const bf16_t* __restrict__ W2T, const float* __restrict__ b2,
    const int* __restrict__ counts, const int* __restrict__ offsets,
    const int* __restrict__ bucket_tok, const float* __restrict__ bucket_w,
    const int* __restrict__ wl_e, const int* __restrict__ wl_m, const int* __restrict__ n_work,
    float* __restrict__ out) {
  const int widx = blockIdx.x;
  if (widx >= *n_work) return;
  const int e = wl_e[widx];
  const int m_base = wl_m[widx];
  const int n_e = counts[e];
  const int n_base = blockIdx.y * 256;
  const int off = offsets[e];

  __shared__ bf16_t As[2][256 * 64];
  __shared__ bf16_t Bs[2][256 * 64];

  const int tid = threadIdx.x;
  const int w = tid >> 6;
  const int lane = tid & 63;
  const int quad = lane >> 4;
  const int lrow = lane & 15;
  const int wm = w >> 2;
  const int wn = w & 3;

  const int srow = lane >> 3;
  const int kch = (((lane & 7) ^ (srow & 7)) * 8);
  const bf16_t* ga[4];
#pragma unroll
  for (int g = 0; g < 4; ++g) {
    int r = m_base + w * 32 + g * 8 + srow;
    if (r >= n_e) r = n_e - 1;
    ga[g] = h1 + (size_t)(off + r) * ID + kch;  // A rows are bucket-contiguous here
  }
  const bf16_t* gb[4];
#pragma unroll
  for (int g = 0; g < 4; ++g)
    gb[g] = W2T + ((size_t)e * HD + n_base + w * 32 + g * 8 + srow) * ID + kch;
  int aofs[4], bofs[4];
#pragma unroll
  for (int g = 0; g < 4; ++g) {
    aofs[g] = (w * 32 + g * 8) * 64 + lane * 8;
    bofs[g] = (w * 32 + g * 8) * 64 + lane * 8;
  }

  f32x4 acc[8][4];
#pragma unroll
  for (int mt = 0; mt < 8; ++mt)
#pragma unroll
    for (int nt = 0; nt < 4; ++nt)
#pragma unroll
      for (int r = 0; r < 4; ++r) acc[mt][nt][r] = 0.f;

  const int s0 = ((0 * 4 + quad) ^ (lrow & 7)) * 8;
  const int s1 = ((1 * 4 + quad) ^ (lrow & 7)) * 8;

#pragma unroll
  for (int g = 0; g < 4; ++g) GLOAD(ga[g], &As[0][aofs[g]]);
#pragma unroll
  for (int g = 0; g < 4; ++g) GLOAD(gb[g], &Bs[0][bofs[g]]);
  __syncthreads();

#define NT2 (ID / 64)
  for (int kt = 0; kt < NT2; ++kt) {
    const int cur = kt & 1;
    if (kt + 1 < NT2) {
      const int nxt = cur ^ 1;
      const size_t ko = (size_t)(kt + 1) * 64;
#pragma unroll
      for (int g = 0; g < 4; ++g) GLOAD(ga[g] + ko, &As[nxt][aofs[g]]);
#pragma unroll
      for (int g = 0; g < 4; ++g) GLOAD(gb[g] + ko, &Bs[nxt][bofs[g]]);
    }
#pragma unroll
    for (int kk = 0; kk < 2; ++kk) {
      const int sl = kk ? s1 : s0;
      bf16x8 bfr[4];
#pragma unroll
      for (int i = 0; i < 4; ++i)
        bfr[i] = *(const bf16x8*)(&Bs[cur][(wn * 64 + i * 16 + lrow) * 64 + sl]);
#pragma unroll
      for (int mt = 0; mt < 8; ++mt) {
        const bf16x8 af = *(const bf16x8*)(&As[cur][(wm * 128 + mt * 16 + lrow) * 64 + sl]);
#pragma unroll
        for (int nt = 0; nt < 4; ++nt)
          acc[mt][nt] = __builtin_amdgcn_mfma_f32_16x16x32_bf16(af, bfr[nt], acc[mt][nt], 0, 0, 0);
      }
    }
    __syncthreads();
  }

#pragma unroll
  for (int mt = 0; mt < 8; ++mt) {
#pragma unroll
    for (int r = 0; r < 4; ++r) {
      const int gm = m_base + wm * 128 + mt * 16 + quad * 4 + r;
      if (gm < n_e) {
        const int pos = off + gm;
        const int tokid = bucket_tok[pos];
        const float wgt = bucket_w[pos];
        float* orow = out + (size_t)tokid * HD;
#pragma unroll
        for (int nt = 0; nt < 4; ++nt) {
          const int gh = n_base + wn * 64 + nt * 16 + lrow;
          float v = acc[mt][nt][r] + b2[e * HD + gh];
          atomicAdd(orow + gh, wgt * v);
        }
      }
    }
  }
}

extern "C" void kernel_launch(void* const* d_in, const int* in_sizes, int n_in,
                              void* d_out, int out_size, void* d_ws, size_t ws_size,
                              hipStream_t stream) {
  const float* x = (const float*)d_in[0];
  const float* Wg = (const float*)d_in[1];
  const float* W1 = (const float*)d_in[2];
  const float* b1 = (const float*)d_in[3];
  const float* W2 = (const float*)d_in[4];
  const float* b2 = (const float*)d_in[5];
  float* out = (float*)d_out;
  char* ws = (char*)d_ws;

  int* counts = (int*)(ws + WS_COUNTS);
  int* offsets = (int*)(ws + WS_OFFSETS);
  int* bucket_tok = (int*)(ws + WS_BTOK);
  float* bucket_w = (float*)(ws + WS_BW);
  int* tok_e = (int*)(ws + WS_TE);
  float* tok_w = (float*)(ws + WS_TW);
  int* wl_e = (int*)(ws + WS_WL);
  int* wl_m = wl_e + MAXWL;
  int* n_work = wl_m + MAXWL;
  int* blk_cnt = (int*)(ws + WS_BLKC);
  int* blk_base = (int*)(ws + WS_BLKB);
  bf16_t* xb = (bf16_t*)(ws + WS_XB);
  bf16_t* h1 = (bf16_t*)(ws + WS_H1);
  bf16_t* WT = (bf16_t*)(ws + WS_WT);

  zero_kernel<<<(TOKS * HD / 4) / 256, 256, 0, stream>>>(out);
  convert_kernel<<<TOKS * HD / (256 * 8), 256, 0, stream>>>(x, xb);
  gate_kernel<<<TOKS / 8, 256, 0, stream>>>(x, Wg, tok_e, tok_w);
  hist_kernel<<<TOKS * 2 / 256, 256, 0, stream>>>(tok_e, blk_cnt);
  scan_kernel<<<1, 64, 0, stream>>>(blk_cnt, counts, offsets, blk_base, wl_e, wl_m, n_work);
  scatter_kernel<<<TOKS * 2 / 256, 256, 0, stream>>>(tok_e, tok_w, blk_base, bucket_tok,
                                                     bucket_w);
  transpose_convert_kernel<<<dim3(HD / 64, ID / 64, NE), 256, 0, stream>>>(W1, WT, HD, ID);
  gemm1_kernel<<<dim3(MAXWL, ID / 256), 512, 0, stream>>>(xb, WT, b1, counts, offsets, bucket_tok,
                                                          wl_e, wl_m, n_work, h1);
  transpose_convert_kernel<<<dim3(ID / 64, HD / 64, NE), 256, 0, stream>>>(W2, WT, ID, HD);
  gemm2_kernel<<<dim3(MAXWL, HD / 256), 512, 0, stream>>>(h1, WT, b2, counts, offsets,
                                                          bucket_tok, bucket_w, wl_e, wl_m,
                                                          n_work, out);
}

// Round 9
// 480.185 us; speedup vs baseline: 1.3507x; 1.3140x over previous
//
#include <hip/hip_runtime.h>
#include <math.h>

#define TOKS 8192
#define HD 1024
#define ID 2048
#define NE 8

typedef __bf16 bf16_t;
typedef __bf16 bf16x8 __attribute__((ext_vector_type(8)));
typedef float f32x4 __attribute__((ext_vector_type(4)));

// async global->LDS, 16 bytes per lane. LDS dest: wave-uniform base + lane*16.
#define GLOAD(gp, lp)                                                \
  __builtin_amdgcn_global_load_lds(                                  \
      (const __attribute__((address_space(1))) void*)(gp),           \
      (__attribute__((address_space(3))) void*)(lp), 16, 0, 0)

#define WAITV(N) asm volatile("s_waitcnt vmcnt(" #N ")" ::: "memory")
#define WAITL0() asm volatile("s_waitcnt lgkmcnt(0)" ::: "memory")

// ---------------- workspace layout (bytes) ----------------
#define WS_COUNTS 0
#define WS_OFFSETS 32
#define WS_BTOK 128
#define WS_BW (128 + 65536)
#define WS_TE (128 + 2 * 65536)
#define WS_TW (128 + 3 * 65536)
#define WS_WL 263168ull
#define WS_BLKC 266240ull                     // blk_cnt  [64][8] int
#define WS_BLKB 270336ull                     // blk_base [64][8] int
#define WS_POS 274432ull                      // pos_of   [16384] int (64 KB)
#define WS_XB 524288ull                       // bf16 x  [8192][1024]  = 16.78 MB
#define WS_H1 (WS_XB + 16777216ull)           // bf16 h1 [16384][2048] = 67.1 MB
#define WS_WT (WS_H1 + 67108864ull)           // bf16 WT (W1T then W2T) = 33.55 MB
#define WS_Y (WS_WT + 33554432ull)            // bf16 y  [16384][1024] = 33.55 MB (ends ~151.5 MB)

#define MAXWL 144
#define BM 128  // m-tile (rows of token bucket) — r5-verified best geometry

// ---------------- x -> bf16 convert: pure streaming ----
__global__ void convert_kernel(const float* __restrict__ x, bf16_t* __restrict__ xb) {
  const size_t i = ((size_t)blockIdx.x * 256 + threadIdx.x) * 8;
  const float4 a = *(const float4*)(x + i);
  const float4 b = *(const float4*)(x + i + 4);
  bf16_t o[8] = {(bf16_t)a.x, (bf16_t)a.y, (bf16_t)a.z, (bf16_t)a.w,
                 (bf16_t)b.x, (bf16_t)b.y, (bf16_t)b.z, (bf16_t)b.w};
  *(uint4*)(xb + i) = *(uint4*)o;
}

// ---------------- gating: top-2 + weights, no atomics (r5 verified) ----
__global__ __launch_bounds__(256) void gate_kernel(const float* __restrict__ x,
                                                   const float* __restrict__ Wg,
                                                   int* __restrict__ tok_e,
                                                   float* __restrict__ tok_w) {
  __shared__ float WgT[NE][HD];  // 32 KB
  const int tid = threadIdx.x;
#pragma unroll
  for (int i = 0; i < NE * HD / 256; ++i) {
    const int idx = i * 256 + tid;
    WgT[idx & 7][idx >> 3] = Wg[idx];
  }
  __syncthreads();
  const int wv = tid >> 6;
  const int lane = tid & 63;
#pragma unroll
  for (int s = 0; s < 2; ++s) {
    const int t = blockIdx.x * 8 + wv * 2 + s;
    const float* xrow = x + (size_t)t * HD;
    float acc[NE];
#pragma unroll
    for (int e = 0; e < NE; ++e) acc[e] = 0.f;
#pragma unroll
    for (int i = 0; i < 16; ++i) {
      const int h = i * 64 + lane;
      const float xv = xrow[h];
#pragma unroll
      for (int e = 0; e < NE; ++e) acc[e] += xv * WgT[e][h];
    }
#pragma unroll
    for (int off = 32; off >= 1; off >>= 1) {
#pragma unroll
      for (int e = 0; e < NE; ++e) acc[e] += __shfl_xor(acc[e], off);
    }
    if (lane == 0) {
      int i1 = 0;
      float l1 = acc[0];
#pragma unroll
      for (int e = 1; e < NE; ++e)
        if (acc[e] > l1) { l1 = acc[e]; i1 = e; }
      int i2 = -1;
      float l2 = -3.4e38f;
#pragma unroll
      for (int e = 0; e < NE; ++e)
        if (e != i1 && acc[e] > l2) { l2 = acc[e]; i2 = e; }
      const float q = expf(l2 - l1);
      const float w1 = 1.f / (1.f + q);
      tok_e[2 * t] = i1;
      tok_e[2 * t + 1] = i2;
      tok_w[2 * t] = w1;
      tok_w[2 * t + 1] = q * w1;
    }
  }
}

// ---------------- histogram: per-block per-expert counts via wave ballots ----
__global__ __launch_bounds__(256) void hist_kernel(const int* __restrict__ tok_e,
                                                   int* __restrict__ blk_cnt) {
  __shared__ int wcnt[4][NE];
  const int tid = threadIdx.x;
  const int idx = blockIdx.x * 256 + tid;
  const int e = tok_e[idx];
  const int w = tid >> 6;
  const int lane = tid & 63;
#pragma unroll
  for (int e0 = 0; e0 < NE; ++e0) {
    const unsigned long long m = __ballot(e == e0);
    if (lane == 0) wcnt[w][e0] = __popcll(m);
  }
  __syncthreads();
  if (tid < NE)
    blk_cnt[blockIdx.x * NE + tid] =
        wcnt[0][tid] + wcnt[1][tid] + wcnt[2][tid] + wcnt[3][tid];
}

// ---------------- scan: one wave; 64-wide shfl prefix-sum per expert ----
__global__ void scan_kernel(const int* __restrict__ blk_cnt, int* __restrict__ counts,
                            int* __restrict__ offsets, int* __restrict__ blk_base,
                            int* __restrict__ wl_e, int* __restrict__ wl_m,
                            int* __restrict__ n_work) {
  const int b = threadIdx.x;  // 0..63, one per scatter block
  int c[NE], pre[NE], tot[NE];
#pragma unroll
  for (int e = 0; e < NE; ++e) c[e] = blk_cnt[b * NE + e];
#pragma unroll
  for (int e = 0; e < NE; ++e) {
    int v = c[e];
#pragma unroll
    for (int off = 1; off < 64; off <<= 1) {
      const int u = __shfl_up(v, off);
      if (b >= off) v += u;
    }
    pre[e] = v - c[e];          // exclusive prefix over blocks
    tot[e] = __shfl(v, 63);     // expert total
  }
  int off_[NE];
  int s = 0;
#pragma unroll
  for (int e = 0; e < NE; ++e) {
    off_[e] = s;
    s += tot[e];
  }
#pragma unroll
  for (int e = 0; e < NE; ++e) blk_base[b * NE + e] = off_[e] + pre[e];
  if (b == 0) {
    int idx = 0;
    for (int e = 0; e < NE; ++e) {
      counts[e] = tot[e];
      offsets[e] = off_[e];
      for (int m = 0; m < tot[e] && idx < MAXWL; m += BM) {
        wl_e[idx] = e;
        wl_m[idx] = m;
        ++idx;
      }
    }
    *n_work = idx;
  }
}

// ---------------- scatter: position = blk_base + wave prefix + ballot rank ----
// Also records pos_of[idx] so the combine kernel can find each token's 2 rows.
__global__ __launch_bounds__(256) void scatter_kernel(const int* __restrict__ tok_e,
                                                      const float* __restrict__ tok_w,
                                                      const int* __restrict__ blk_base,
                                                      int* __restrict__ bucket_tok,
                                                      float* __restrict__ bucket_w,
                                                      int* __restrict__ pos_of) {
  __shared__ int wcnt[4][NE];
  const int tid = threadIdx.x;
  const int idx = blockIdx.x * 256 + tid;
  const int e = tok_e[idx];
  const int w = tid >> 6;
  const int lane = tid & 63;
  unsigned long long mym = 0;
#pragma unroll
  for (int e0 = 0; e0 < NE; ++e0) {
    const unsigned long long m = __ballot(e == e0);
    if (lane == 0) wcnt[w][e0] = __popcll(m);
    if (e0 == e) mym = m;
  }
  __syncthreads();
  int base = blk_base[blockIdx.x * NE + e];
  for (int w2 = 0; w2 < w; ++w2) base += wcnt[w2][e];
  const int rank = __popcll(mym & ((1ull << lane) - 1ull));
  const int pos = base + rank;
  bucket_tok[pos] = idx >> 1;
  bucket_w[pos] = tok_w[idx];
  pos_of[idx] = pos;
}

// ---------------- transpose+convert: src [E][K][N] f32 -> dst [E][N][K] bf16 ----
__global__ __launch_bounds__(256) void transpose_convert_kernel(const float* __restrict__ src,
                                                                bf16_t* __restrict__ dst, int K,
                                                                int N) {
  __shared__ float tile[64][65];
  const int e = blockIdx.z;
  const int k0 = blockIdx.x * 64;
  const int n0 = blockIdx.y * 64;
  const float* s = src + (size_t)e * K * N;
  bf16_t* d = dst + (size_t)e * K * N;
  const int t = threadIdx.x;
  const int c = t & 63;
  const int r4 = t >> 6;
#pragma unroll
  for (int p = 0; p < 16; ++p) {
    const int r = p * 4 + r4;
    tile[r][c] = s[(size_t)(k0 + r) * N + n0 + c];
  }
  __syncthreads();
  const int kc = t & 7;
  const int nb = t >> 3;
#pragma unroll
  for (int p = 0; p < 2; ++p) {
    const int n = p * 32 + nb;
    bf16_t o[8];
#pragma unroll
    for (int j = 0; j < 8; ++j) o[j] = (bf16_t)tile[kc * 8 + j][n];
    *(uint4*)(d + (size_t)(n0 + n) * K + k0 + kc * 8) = *(uint4*)o;
  }
}

// ---------------- expert GEMMs: 128x128 tile, 3-buffer counted-vmcnt pipeline ----
// r5-verified geometry (best measured: ~191 us/gemm, 360 TF). r7/r8 falsified
// bigger tiles (1 blk/CU pins at ~250 us regardless of per-barrier work):
// inter-block TLP at 3 blocks/CU is what this problem rewards.

__global__ __launch_bounds__(256, 3) void gemm1_kernel(
    const bf16_t* __restrict__ xb, const bf16_t* __restrict__ W1T, const float* __restrict__ b1,
    const int* __restrict__ counts, const int* __restrict__ offsets,
    const int* __restrict__ bucket_tok, const int* __restrict__ wl_e,
    const int* __restrict__ wl_m, const int* __restrict__ n_work, bf16_t* __restrict__ h1) {
  const int widx = blockIdx.x;
  if (widx >= *n_work) return;
  const int e = wl_e[widx];
  const int m_base = wl_m[widx];
  const int n_e = counts[e];
  const int n_base = blockIdx.y * 128;
  const int off = offsets[e];

  __shared__ bf16_t As[3][128 * 32];  // 8 KB each
  __shared__ bf16_t Bs[3][128 * 32];

  const int tid = threadIdx.x;
  const int w = tid >> 6;
  const int lane = tid & 63;
  const int quad = lane >> 4;
  const int lrow = lane & 15;
  const int wm = w >> 1;   // 64-row half
  const int wn = w & 1;    // 64-col half

  const int srow = lane >> 2;                       // 16 rows per GLOAD
  const int kch = (((lane & 3) ^ (srow & 3)) * 8);  // pre-swizzled source chunk
  int r0 = m_base + w * 32 + srow;
  int r1 = r0 + 16;
  if (r0 >= n_e) r0 = n_e - 1;
  if (r1 >= n_e) r1 = n_e - 1;
  const bf16_t* ga0 = xb + (size_t)bucket_tok[off + r0] * HD + kch;
  const bf16_t* ga1 = xb + (size_t)bucket_tok[off + r1] * HD + kch;
  const bf16_t* gb0 = W1T + ((size_t)e * ID + n_base + w * 32 + srow) * HD + kch;
  const bf16_t* gb1 = gb0 + (size_t)16 * HD;
  const int laofs0 = w * 1024 + lane * 8;  // rows w*32.. in [128][32]
  const int laofs1 = laofs0 + 512;         // +16 rows

  f32x4 acc[4][4];
#pragma unroll
  for (int mt = 0; mt < 4; ++mt)
#pragma unroll
    for (int nt = 0; nt < 4; ++nt)
#pragma unroll
      for (int r = 0; r < 4; ++r) acc[mt][nt][r] = 0.f;

  // prologue: stage tiles 0 and 1 (8 outstanding GLOADs/wave)
#pragma unroll
  for (int p = 0; p < 2; ++p) {
    const size_t ko = (size_t)p * 32;
    GLOAD(ga0 + ko, &As[p][laofs0]);
    GLOAD(ga1 + ko, &As[p][laofs1]);
    GLOAD(gb0 + ko, &Bs[p][laofs0]);
    GLOAD(gb1 + ko, &Bs[p][laofs1]);
  }

#define NT1 (HD / 32)
  for (int kt = 0; kt < NT1; ++kt) {
    WAITL0();                          // prior iter's ds_reads done (per-wave)
    __builtin_amdgcn_s_barrier();      // #1: buf[(kt+2)%3] free to overwrite
    if (kt + 2 < NT1) {
      const int nxt = (kt + 2) % 3;
      const size_t ko = (size_t)(kt + 2) * 32;
      GLOAD(ga0 + ko, &As[nxt][laofs0]);
      GLOAD(ga1 + ko, &As[nxt][laofs1]);
      GLOAD(gb0 + ko, &Bs[nxt][laofs0]);
      GLOAD(gb1 + ko, &Bs[nxt][laofs1]);
      WAITV(8);                        // tile kt landed; kt+1,kt+2 in flight
    } else if (kt + 1 < NT1) {
      WAITV(4);
    } else {
      WAITV(0);
    }
    __builtin_amdgcn_s_barrier();      // #2: tile kt visible to all waves
    __builtin_amdgcn_sched_barrier(0); // fence: no ds_read hoists above
    const int cur = kt % 3;
    const int slot = (quad ^ (lrow & 3)) * 8;
    bf16x8 af[4], bfr[4];
#pragma unroll
    for (int i = 0; i < 4; ++i) {
      af[i] = *(const bf16x8*)(&As[cur][(wm * 64 + i * 16 + lrow) * 32 + slot]);
      bfr[i] = *(const bf16x8*)(&Bs[cur][(wn * 64 + i * 16 + lrow) * 32 + slot]);
    }
#pragma unroll
    for (int mt = 0; mt < 4; ++mt)
#pragma unroll
      for (int nt = 0; nt < 4; ++nt)
        acc[mt][nt] =
            __builtin_amdgcn_mfma_f32_16x16x32_bf16(af[mt], bfr[nt], acc[mt][nt], 0, 0, 0);
  }

#pragma unroll
  for (int mt = 0; mt < 4; ++mt) {
#pragma unroll
    for (int r = 0; r < 4; ++r) {
      const int gm = m_base + wm * 64 + mt * 16 + quad * 4 + r;
      if (gm < n_e) {
        bf16_t* orow = h1 + (size_t)(off + gm) * ID;
#pragma unroll
        for (int nt = 0; nt < 4; ++nt) {
          const int gi = n_base + wn * 64 + nt * 16 + lrow;
          float v = acc[mt][nt][r] + b1[e * ID + gi];
          v = 0.5f * v * (1.f + erff(v * 0.70710678118654752f));  // exact-erf GELU
          orow[gi] = (bf16_t)v;
        }
      }
    }
  }
}

// gemm2: identical loop; epilogue now stores y[pos] = row + b2 (bf16, NO
// atomics). r8 post-mortem: 16.7M same-pair f32 atomicAdds ~= 50-70 us of
// L2-RMW serialization (r3 split-K doubling cost +70 us). Combine applies
// gate weights and writes out once.
__global__ __launch_bounds__(256, 3) void gemm2_kernel(
    const bf16_t* __restrict__ h1, const bf16_t* __restrict__ W2T, const float* __restrict__ b2,
    const int* __restrict__ counts, const int* __restrict__ offsets,
    const int* __restrict__ wl_e, const int* __restrict__ wl_m, const int* __restrict__ n_work,
    bf16_t* __restrict__ y) {
  const int widx = blockIdx.x;
  if (widx >= *n_work) return;
  const int e = wl_e[widx];
  const int m_base = wl_m[widx];
  const int n_e = counts[e];
  const int n_base = blockIdx.y * 128;
  const int off = offsets[e];

  __shared__ bf16_t As[3][128 * 32];
  __shared__ bf16_t Bs[3][128 * 32];

  const int tid = threadIdx.x;
  const int w = tid >> 6;
  const int lane = tid & 63;
  const int quad = lane >> 4;
  const int lrow = lane & 15;
  const int wm = w >> 1;
  const int wn = w & 1;

  const int srow = lane >> 2;
  const int kch = (((lane & 3) ^ (srow & 3)) * 8);
  int r0 = m_base + w * 32 + srow;
  int r1 = r0 + 16;
  if (r0 >= n_e) r0 = n_e - 1;
  if (r1 >= n_e) r1 = n_e - 1;
  const bf16_t* ga0 = h1 + (size_t)(off + r0) * ID + kch;
  const bf16_t* ga1 = h1 + (size_t)(off + r1) * ID + kch;
  const bf16_t* gb0 = W2T + ((size_t)e * HD + n_base + w * 32 + srow) * ID + kch;
  const bf16_t* gb1 = gb0 + (size_t)16 * ID;
  const int laofs0 = w * 1024 + lane * 8;
  const int laofs1 = laofs0 + 512;

  f32x4 acc[4][4];
#pragma unroll
  for (int mt = 0; mt < 4; ++mt)
#pragma unroll
    for (int nt = 0; nt < 4; ++nt)
#pragma unroll
      for (int r = 0; r < 4; ++r) acc[mt][nt][r] = 0.f;

#pragma unroll
  for (int p = 0; p < 2; ++p) {
    const size_t ko = (size_t)p * 32;
    GLOAD(ga0 + ko, &As[p][laofs0]);
    GLOAD(ga1 + ko, &As[p][laofs1]);
    GLOAD(gb0 + ko, &Bs[p][laofs0]);
    GLOAD(gb1 + ko, &Bs[p][laofs1]);
  }

#define NT2 (ID / 32)
  for (int kt = 0; kt < NT2; ++kt) {
    WAITL0();
    __builtin_amdgcn_s_barrier();
    if (kt + 2 < NT2) {
      const int nxt = (kt + 2) % 3;
      const size_t ko = (size_t)(kt + 2) * 32;
      GLOAD(ga0 + ko, &As[nxt][laofs0]);
      GLOAD(ga1 + ko, &As[nxt][laofs1]);
      GLOAD(gb0 + ko, &Bs[nxt][laofs0]);
      GLOAD(gb1 + ko, &Bs[nxt][laofs1]);
      WAITV(8);
    } else if (kt + 1 < NT2) {
      WAITV(4);
    } else {
      WAITV(0);
    }
    __builtin_amdgcn_s_barrier();
    __builtin_amdgcn_sched_barrier(0);
    const int cur = kt % 3;
    const int slot = (quad ^ (lrow & 3)) * 8;
    bf16x8 af[4], bfr[4];
#pragma unroll
    for (int i = 0; i < 4; ++i) {
      af[i] = *(const bf16x8*)(&As[cur][(wm * 64 + i * 16 + lrow) * 32 + slot]);
      bfr[i] = *(const bf16x8*)(&Bs[cur][(wn * 64 + i * 16 + lrow) * 32 + slot]);
    }
#pragma unroll
    for (int mt = 0; mt < 4; ++mt)
#pragma unroll
      for (int nt = 0; nt < 4; ++nt)
        acc[mt][nt] =
            __builtin_amdgcn_mfma_f32_16x16x32_bf16(af[mt], bfr[nt], acc[mt][nt], 0, 0, 0);
  }

#pragma unroll
  for (int mt = 0; mt < 4; ++mt) {
#pragma unroll
    for (int r = 0; r < 4; ++r) {
      const int gm = m_base + wm * 64 + mt * 16 + quad * 4 + r;
      if (gm < n_e) {
        bf16_t* orow = y + (size_t)(off + gm) * HD;
#pragma unroll
        for (int nt = 0; nt < 4; ++nt) {
          const int gh = n_base + wn * 64 + nt * 16 + lrow;
          orow[gh] = (bf16_t)(acc[mt][nt][r] + b2[e * HD + gh]);  // plain store
        }
      }
    }
  }
}

// ---------------- combine: out[t] = w1*y[p1] + w2*y[p2] (replaces zero+atomics) ----
__global__ __launch_bounds__(256) void combine_kernel(const bf16_t* __restrict__ y,
                                                      const int* __restrict__ pos_of,
                                                      const float* __restrict__ tok_w,
                                                      float* __restrict__ out) {
  const int gid = blockIdx.x * 256 + threadIdx.x;
  const int t = gid >> 7;             // 128 8-wide chunks per token row
  const int c8 = (gid & 127) * 8;
  const int p1 = pos_of[2 * t];
  const int p2 = pos_of[2 * t + 1];
  const float w1 = tok_w[2 * t];
  const float w2 = tok_w[2 * t + 1];
  const bf16x8 a = *(const bf16x8*)(y + (size_t)p1 * HD + c8);
  const bf16x8 b = *(const bf16x8*)(y + (size_t)p2 * HD + c8);
  float* op = out + (size_t)t * HD + c8;
#pragma unroll
  for (int j = 0; j < 8; ++j) op[j] = w1 * (float)a[j] + w2 * (float)b[j];
}

extern "C" void kernel_launch(void* const* d_in, const int* in_sizes, int n_in,
                              void* d_out, int out_size, void* d_ws, size_t ws_size,
                              hipStream_t stream) {
  const float* x = (const float*)d_in[0];
  const float* Wg = (const float*)d_in[1];
  const float* W1 = (const float*)d_in[2];
  const float* b1 = (const float*)d_in[3];
  const float* W2 = (const float*)d_in[4];
  const float* b2 = (const float*)d_in[5];
  float* out = (float*)d_out;
  char* ws = (char*)d_ws;

  int* counts = (int*)(ws + WS_COUNTS);
  int* offsets = (int*)(ws + WS_OFFSETS);
  int* bucket_tok = (int*)(ws + WS_BTOK);
  float* bucket_w = (float*)(ws + WS_BW);
  int* tok_e = (int*)(ws + WS_TE);
  float* tok_w = (float*)(ws + WS_TW);
  int* wl_e = (int*)(ws + WS_WL);
  int* wl_m = wl_e + MAXWL;
  int* n_work = wl_m + MAXWL;
  int* blk_cnt = (int*)(ws + WS_BLKC);
  int* blk_base = (int*)(ws + WS_BLKB);
  int* pos_of = (int*)(ws + WS_POS);
  bf16_t* xb = (bf16_t*)(ws + WS_XB);
  bf16_t* h1 = (bf16_t*)(ws + WS_H1);
  bf16_t* WT = (bf16_t*)(ws + WS_WT);
  bf16_t* y = (bf16_t*)(ws + WS_Y);

  convert_kernel<<<TOKS * HD / (256 * 8), 256, 0, stream>>>(x, xb);
  gate_kernel<<<TOKS / 8, 256, 0, stream>>>(x, Wg, tok_e, tok_w);
  hist_kernel<<<TOKS * 2 / 256, 256, 0, stream>>>(tok_e, blk_cnt);
  scan_kernel<<<1, 64, 0, stream>>>(blk_cnt, counts, offsets, blk_base, wl_e, wl_m, n_work);
  scatter_kernel<<<TOKS * 2 / 256, 256, 0, stream>>>(tok_e, tok_w, blk_base, bucket_tok,
                                                     bucket_w, pos_of);
  transpose_convert_kernel<<<dim3(HD / 64, ID / 64, NE), 256, 0, stream>>>(W1, WT, HD, ID);
  gemm1_kernel<<<dim3(MAXWL, ID / 128), 256, 0, stream>>>(xb, WT, b1, counts, offsets, bucket_tok,
                                                          wl_e, wl_m, n_work, h1);
  transpose_convert_kernel<<<dim3(ID / 64, HD / 64, NE), 256, 0, stream>>>(W2, WT, ID, HD);
  gemm2_kernel<<<dim3(MAXWL, HD / 128), 256, 0, stream>>>(h1, WT, b2, counts, offsets, wl_e,
                                                          wl_m, n_work, y);
  combine_kernel<<<TOKS * HD / (256 * 8), 256, 0, stream>>>(y, pos_of, tok_w, out);
}

// Round 10
// 469.169 us; speedup vs baseline: 1.3825x; 1.0235x over previous
//
#include <hip/hip_runtime.h>
#include <math.h>

#define TOKS 8192
#define HD 1024
#define ID 2048
#define NE 8

typedef __bf16 bf16_t;
typedef __bf16 bf16x8 __attribute__((ext_vector_type(8)));
typedef float f32x4 __attribute__((ext_vector_type(4)));

// async global->LDS, 16 bytes per lane. LDS dest: wave-uniform base + lane*16.
#define GLOAD(gp, lp)                                                \
  __builtin_amdgcn_global_load_lds(                                  \
      (const __attribute__((address_space(1))) void*)(gp),           \
      (__attribute__((address_space(3))) void*)(lp), 16, 0, 0)

#define WAITV(N) asm volatile("s_waitcnt vmcnt(" #N ")" ::: "memory")
#define WAITL0() asm volatile("s_waitcnt lgkmcnt(0)" ::: "memory")

// ---------------- workspace layout (bytes) ----------------
#define WS_COUNTS 0
#define WS_OFFSETS 32
#define WS_BTOK 128
#define WS_BW (128 + 65536)
#define WS_TE (128 + 2 * 65536)
#define WS_TW (128 + 3 * 65536)
#define WS_WL 263168ull
#define WS_BLKC 266240ull                     // blk_cnt  [64][8] int
#define WS_BLKB 270336ull                     // blk_base [64][8] int
#define WS_POS 274432ull                      // pos_of   [16384] int (64 KB)
#define WS_XB 524288ull                       // bf16 x  [8192][1024]  = 16.78 MB
#define WS_H1 (WS_XB + 16777216ull)           // bf16 h1 [16384][2048] = 67.1 MB
#define WS_WT (WS_H1 + 67108864ull)           // bf16 WT (W1T then W2T) = 33.55 MB
#define WS_Y (WS_WT + 33554432ull)            // bf16 y  [16384][1024] = 33.55 MB (ends ~151.5 MB)

#define MAXWL 144
#define BM 128  // m-tile (rows of token bucket) — r5/r9-verified best geometry

// ---------------- gating + fused x->bf16 convert (r9: separate convert was a
// redundant 33MB pass; gate touches every x element anyway) ----------------
__global__ __launch_bounds__(256) void gate_kernel(const float* __restrict__ x,
                                                   const float* __restrict__ Wg,
                                                   bf16_t* __restrict__ xb,
                                                   int* __restrict__ tok_e,
                                                   float* __restrict__ tok_w) {
  __shared__ float WgT[NE][HD];  // 32 KB
  const int tid = threadIdx.x;
#pragma unroll
  for (int i = 0; i < NE * HD / 256; ++i) {
    const int idx = i * 256 + tid;
    WgT[idx & 7][idx >> 3] = Wg[idx];
  }
  __syncthreads();
  const int wv = tid >> 6;
  const int lane = tid & 63;
#pragma unroll
  for (int s = 0; s < 2; ++s) {
    const int t = blockIdx.x * 8 + wv * 2 + s;
    const float* xrow = x + (size_t)t * HD;
    bf16_t* xbrow = xb + (size_t)t * HD;
    float acc[NE];
#pragma unroll
    for (int e = 0; e < NE; ++e) acc[e] = 0.f;
#pragma unroll
    for (int i = 0; i < 16; ++i) {
      const int h = i * 64 + lane;
      const float xv = xrow[h];
      xbrow[h] = (bf16_t)xv;  // fused convert: 64 lanes x 2B = 128B contiguous
#pragma unroll
      for (int e = 0; e < NE; ++e) acc[e] += xv * WgT[e][h];
    }
#pragma unroll
    for (int off = 32; off >= 1; off >>= 1) {
#pragma unroll
      for (int e = 0; e < NE; ++e) acc[e] += __shfl_xor(acc[e], off);
    }
    if (lane == 0) {
      int i1 = 0;
      float l1 = acc[0];
#pragma unroll
      for (int e = 1; e < NE; ++e)
        if (acc[e] > l1) { l1 = acc[e]; i1 = e; }
      int i2 = -1;
      float l2 = -3.4e38f;
#pragma unroll
      for (int e = 0; e < NE; ++e)
        if (e != i1 && acc[e] > l2) { l2 = acc[e]; i2 = e; }
      const float q = expf(l2 - l1);
      const float w1 = 1.f / (1.f + q);
      tok_e[2 * t] = i1;
      tok_e[2 * t + 1] = i2;
      tok_w[2 * t] = w1;
      tok_w[2 * t + 1] = q * w1;
    }
  }
}

// ---------------- histogram: per-block per-expert counts via wave ballots ----
__global__ __launch_bounds__(256) void hist_kernel(const int* __restrict__ tok_e,
                                                   int* __restrict__ blk_cnt) {
  __shared__ int wcnt[4][NE];
  const int tid = threadIdx.x;
  const int idx = blockIdx.x * 256 + tid;
  const int e = tok_e[idx];
  const int w = tid >> 6;
  const int lane = tid & 63;
#pragma unroll
  for (int e0 = 0; e0 < NE; ++e0) {
    const unsigned long long m = __ballot(e == e0);
    if (lane == 0) wcnt[w][e0] = __popcll(m);
  }
  __syncthreads();
  if (tid < NE)
    blk_cnt[blockIdx.x * NE + tid] =
        wcnt[0][tid] + wcnt[1][tid] + wcnt[2][tid] + wcnt[3][tid];
}

// ---------------- scan: one wave; 64-wide shfl prefix-sum per expert ----
__global__ void scan_kernel(const int* __restrict__ blk_cnt, int* __restrict__ counts,
                            int* __restrict__ offsets, int* __restrict__ blk_base,
                            int* __restrict__ wl_e, int* __restrict__ wl_m,
                            int* __restrict__ n_work) {
  const int b = threadIdx.x;  // 0..63, one per scatter block
  int c[NE], pre[NE], tot[NE];
#pragma unroll
  for (int e = 0; e < NE; ++e) c[e] = blk_cnt[b * NE + e];
#pragma unroll
  for (int e = 0; e < NE; ++e) {
    int v = c[e];
#pragma unroll
    for (int off = 1; off < 64; off <<= 1) {
      const int u = __shfl_up(v, off);
      if (b >= off) v += u;
    }
    pre[e] = v - c[e];          // exclusive prefix over blocks
    tot[e] = __shfl(v, 63);     // expert total
  }
  int off_[NE];
  int s = 0;
#pragma unroll
  for (int e = 0; e < NE; ++e) {
    off_[e] = s;
    s += tot[e];
  }
#pragma unroll
  for (int e = 0; e < NE; ++e) blk_base[b * NE + e] = off_[e] + pre[e];
  if (b == 0) {
    int idx = 0;
    for (int e = 0; e < NE; ++e) {
      counts[e] = tot[e];
      offsets[e] = off_[e];
      for (int m = 0; m < tot[e] && idx < MAXWL; m += BM) {
        wl_e[idx] = e;
        wl_m[idx] = m;
        ++idx;
      }
    }
    *n_work = idx;
  }
}

// ---------------- scatter: position = blk_base + wave prefix + ballot rank ----
__global__ __launch_bounds__(256) void scatter_kernel(const int* __restrict__ tok_e,
                                                      const float* __restrict__ tok_w,
                                                      const int* __restrict__ blk_base,
                                                      int* __restrict__ bucket_tok,
                                                      float* __restrict__ bucket_w,
                                                      int* __restrict__ pos_of) {
  __shared__ int wcnt[4][NE];
  const int tid = threadIdx.x;
  const int idx = blockIdx.x * 256 + tid;
  const int e = tok_e[idx];
  const int w = tid >> 6;
  const int lane = tid & 63;
  unsigned long long mym = 0;
#pragma unroll
  for (int e0 = 0; e0 < NE; ++e0) {
    const unsigned long long m = __ballot(e == e0);
    if (lane == 0) wcnt[w][e0] = __popcll(m);
    if (e0 == e) mym = m;
  }
  __syncthreads();
  int base = blk_base[blockIdx.x * NE + e];
  for (int w2 = 0; w2 < w; ++w2) base += wcnt[w2][e];
  const int rank = __popcll(mym & ((1ull << lane) - 1ull));
  const int pos = base + rank;
  bucket_tok[pos] = idx >> 1;
  bucket_w[pos] = tok_w[idx];
  pos_of[idx] = pos;
}

// ---------------- transpose+convert: src [E][K][N] f32 -> dst [E][N][K] bf16 ----
__global__ __launch_bounds__(256) void transpose_convert_kernel(const float* __restrict__ src,
                                                                bf16_t* __restrict__ dst, int K,
                                                                int N) {
  __shared__ float tile[64][65];
  const int e = blockIdx.z;
  const int k0 = blockIdx.x * 64;
  const int n0 = blockIdx.y * 64;
  const float* s = src + (size_t)e * K * N;
  bf16_t* d = dst + (size_t)e * K * N;
  const int t = threadIdx.x;
  const int c = t & 63;
  const int r4 = t >> 6;
#pragma unroll
  for (int p = 0; p < 16; ++p) {
    const int r = p * 4 + r4;
    tile[r][c] = s[(size_t)(k0 + r) * N + n0 + c];
  }
  __syncthreads();
  const int kc = t & 7;
  const int nb = t >> 3;
#pragma unroll
  for (int p = 0; p < 2; ++p) {
    const int n = p * 32 + nb;
    bf16_t o[8];
#pragma unroll
    for (int j = 0; j < 8; ++j) o[j] = (bf16_t)tile[kc * 8 + j][n];
    *(uint4*)(d + (size_t)(n0 + n) * K + k0 + kc * 8) = *(uint4*)o;
  }
}

// ---------------- expert GEMMs: 128x128 tile, 3-buffer counted-vmcnt pipeline ----
// r9 analysis: LDS port is the binding resource (48KB/block-iter, ~70% busy at
// 3 blocks/CU); 8.65M conflict-cycles = ~9% of wall sit directly on it.
// Conflict fix (this round): old read slot quad^(lrow&3) put lanes
// {lrow,lrow+4,+8,+12} on one bank-start = 4-way (1.58x, m136). New key uses
// lrow bits [3:2]: slot = (quad ^ ((lrow>>2)&3)), write-side source chunk
// kch = ((lane&3) ^ ((lane>>4)&3)) — each 16-lane phase now covers all 32
// banks exactly 2-way = free. Identity: row[3:2]==lrow[3:2] for all read rows
// and srow[3:2]==(lane>>4)&3 for all staged rows (band offsets are multiples
// of 16), so phys chunk p of row r holds logical chunk p^((r>>2)&3) and reads
// recover logical chunk quad everywhere.

__global__ __launch_bounds__(256, 3) void gemm1_kernel(
    const bf16_t* __restrict__ xb, const bf16_t* __restrict__ W1T, const float* __restrict__ b1,
    const int* __restrict__ counts, const int* __restrict__ offsets,
    const int* __restrict__ bucket_tok, const int* __restrict__ wl_e,
    const int* __restrict__ wl_m, const int* __restrict__ n_work, bf16_t* __restrict__ h1) {
  const int widx = blockIdx.x;
  if (widx >= *n_work) return;
  const int e = wl_e[widx];
  const int m_base = wl_m[widx];
  const int n_e = counts[e];
  const int n_base = blockIdx.y * 128;
  const int off = offsets[e];

  __shared__ bf16_t As[3][128 * 32];  // 8 KB each
  __shared__ bf16_t Bs[3][128 * 32];

  const int tid = threadIdx.x;
  const int w = tid >> 6;
  const int lane = tid & 63;
  const int quad = lane >> 4;
  const int lrow = lane & 15;
  const int wm = w >> 1;   // 64-row half
  const int wn = w & 1;    // 64-col half

  const int srow = lane >> 2;                        // 16 rows per GLOAD
  const int kch = (((lane & 3) ^ ((lane >> 4) & 3)) * 8);  // pre-swizzled source chunk
  int r0 = m_base + w * 32 + srow;
  int r1 = r0 + 16;
  if (r0 >= n_e) r0 = n_e - 1;
  if (r1 >= n_e) r1 = n_e - 1;
  const bf16_t* ga0 = xb + (size_t)bucket_tok[off + r0] * HD + kch;
  const bf16_t* ga1 = xb + (size_t)bucket_tok[off + r1] * HD + kch;
  const bf16_t* gb0 = W1T + ((size_t)e * ID + n_base + w * 32 + srow) * HD + kch;
  const bf16_t* gb1 = gb0 + (size_t)16 * HD;
  const int laofs0 = w * 1024 + lane * 8;  // rows w*32.. in [128][32]
  const int laofs1 = laofs0 + 512;         // +16 rows

  f32x4 acc[4][4];
#pragma unroll
  for (int mt = 0; mt < 4; ++mt)
#pragma unroll
    for (int nt = 0; nt < 4; ++nt)
#pragma unroll
      for (int r = 0; r < 4; ++r) acc[mt][nt][r] = 0.f;

  // prologue: stage tiles 0 and 1 (8 outstanding GLOADs/wave)
#pragma unroll
  for (int p = 0; p < 2; ++p) {
    const size_t ko = (size_t)p * 32;
    GLOAD(ga0 + ko, &As[p][laofs0]);
    GLOAD(ga1 + ko, &As[p][laofs1]);
    GLOAD(gb0 + ko, &Bs[p][laofs0]);
    GLOAD(gb1 + ko, &Bs[p][laofs1]);
  }

  const int slot = (quad ^ ((lrow >> 2) & 3)) * 8;
  int cur = 0;        // kt % 3, carried (no div in loop)
  int pre = 2;        // (kt+2) % 3, carried
#define NT1 (HD / 32)
  for (int kt = 0; kt < NT1; ++kt) {
    WAITL0();                          // prior iter's ds_reads done (per-wave)
    __builtin_amdgcn_s_barrier();      // #1: buf[(kt+2)%3] free to overwrite
    if (kt + 2 < NT1) {
      const size_t ko = (size_t)(kt + 2) * 32;
      GLOAD(ga0 + ko, &As[pre][laofs0]);
      GLOAD(ga1 + ko, &As[pre][laofs1]);
      GLOAD(gb0 + ko, &Bs[pre][laofs0]);
      GLOAD(gb1 + ko, &Bs[pre][laofs1]);
      WAITV(8);                        // tile kt landed; kt+1,kt+2 in flight
    } else if (kt + 1 < NT1) {
      WAITV(4);
    } else {
      WAITV(0);
    }
    __builtin_amdgcn_s_barrier();      // #2: tile kt visible to all waves
    __builtin_amdgcn_sched_barrier(0); // fence: no ds_read hoists above
    bf16x8 af[4], bfr[4];
#pragma unroll
    for (int i = 0; i < 4; ++i) {
      af[i] = *(const bf16x8*)(&As[cur][(wm * 64 + i * 16 + lrow) * 32 + slot]);
      bfr[i] = *(const bf16x8*)(&Bs[cur][(wn * 64 + i * 16 + lrow) * 32 + slot]);
    }
#pragma unroll
    for (int mt = 0; mt < 4; ++mt)
#pragma unroll
      for (int nt = 0; nt < 4; ++nt)
        acc[mt][nt] =
            __builtin_amdgcn_mfma_f32_16x16x32_bf16(af[mt], bfr[nt], acc[mt][nt], 0, 0, 0);
    cur = (cur == 2) ? 0 : cur + 1;
    pre = (pre == 2) ? 0 : pre + 1;
  }

#pragma unroll
  for (int mt = 0; mt < 4; ++mt) {
#pragma unroll
    for (int r = 0; r < 4; ++r) {
      const int gm = m_base + wm * 64 + mt * 16 + quad * 4 + r;
      if (gm < n_e) {
        bf16_t* orow = h1 + (size_t)(off + gm) * ID;
#pragma unroll
        for (int nt = 0; nt < 4; ++nt) {
          const int gi = n_base + wn * 64 + nt * 16 + lrow;
          float v = acc[mt][nt][r] + b1[e * ID + gi];
          v = 0.5f * v * (1.f + erff(v * 0.70710678118654752f));  // exact-erf GELU
          orow[gi] = (bf16_t)v;
        }
      }
    }
  }
}

// gemm2: identical loop; epilogue stores y[pos] = row + b2 (bf16, NO atomics;
// r9-verified). Combine applies gate weights and writes out once.
__global__ __launch_bounds__(256, 3) void gemm2_kernel(
    const bf16_t* __restrict__ h1, const bf16_t* __restrict__ W2T, const float* __restrict__ b2,
    const int* __restrict__ counts, const int* __restrict__ offsets,
    const int* __restrict__ wl_e, const int* __restrict__ wl_m, const int* __restrict__ n_work,
    bf16_t* __restrict__ y) {
  const int widx = blockIdx.x;
  if (widx >= *n_work) return;
  const int e = wl_e[widx];
  const int m_base = wl_m[widx];
  const int n_e = counts[e];
  const int n_base = blockIdx.y * 128;
  const int off = offsets[e];

  __shared__ bf16_t As[3][128 * 32];
  __shared__ bf16_t Bs[3][128 * 32];

  const int tid = threadIdx.x;
  const int w = tid >> 6;
  const int lane = tid & 63;
  const int quad = lane >> 4;
  const int lrow = lane & 15;
  const int wm = w >> 1;
  const int wn = w & 1;

  const int srow = lane >> 2;
  const int kch = (((lane & 3) ^ ((lane >> 4) & 3)) * 8);
  int r0 = m_base + w * 32 + srow;
  int r1 = r0 + 16;
  if (r0 >= n_e) r0 = n_e - 1;
  if (r1 >= n_e) r1 = n_e - 1;
  const bf16_t* ga0 = h1 + (size_t)(off + r0) * ID + kch;
  const bf16_t* ga1 = h1 + (size_t)(off + r1) * ID + kch;
  const bf16_t* gb0 = W2T + ((size_t)e * HD + n_base + w * 32 + srow) * ID + kch;
  const bf16_t* gb1 = gb0 + (size_t)16 * ID;
  const int laofs0 = w * 1024 + lane * 8;
  const int laofs1 = laofs0 + 512;

  f32x4 acc[4][4];
#pragma unroll
  for (int mt = 0; mt < 4; ++mt)
#pragma unroll
    for (int nt = 0; nt < 4; ++nt)
#pragma unroll
      for (int r = 0; r < 4; ++r) acc[mt][nt][r] = 0.f;

#pragma unroll
  for (int p = 0; p < 2; ++p) {
    const size_t ko = (size_t)p * 32;
    GLOAD(ga0 + ko, &As[p][laofs0]);
    GLOAD(ga1 + ko, &As[p][laofs1]);
    GLOAD(gb0 + ko, &Bs[p][laofs0]);
    GLOAD(gb1 + ko, &Bs[p][laofs1]);
  }

  const int slot = (quad ^ ((lrow >> 2) & 3)) * 8;
  int cur = 0;
  int pre = 2;
#define NT2 (ID / 32)
  for (int kt = 0; kt < NT2; ++kt) {
    WAITL0();
    __builtin_amdgcn_s_barrier();
    if (kt + 2 < NT2) {
      const size_t ko = (size_t)(kt + 2) * 32;
      GLOAD(ga0 + ko, &As[pre][laofs0]);
      GLOAD(ga1 + ko, &As[pre][laofs1]);
      GLOAD(gb0 + ko, &Bs[pre][laofs0]);
      GLOAD(gb1 + ko, &Bs[pre][laofs1]);
      WAITV(8);
    } else if (kt + 1 < NT2) {
      WAITV(4);
    } else {
      WAITV(0);
    }
    __builtin_amdgcn_s_barrier();
    __builtin_amdgcn_sched_barrier(0);
    bf16x8 af[4], bfr[4];
#pragma unroll
    for (int i = 0; i < 4; ++i) {
      af[i] = *(const bf16x8*)(&As[cur][(wm * 64 + i * 16 + lrow) * 32 + slot]);
      bfr[i] = *(const bf16x8*)(&Bs[cur][(wn * 64 + i * 16 + lrow) * 32 + slot]);
    }
#pragma unroll
    for (int mt = 0; mt < 4; ++mt)
#pragma unroll
      for (int nt = 0; nt < 4; ++nt)
        acc[mt][nt] =
            __builtin_amdgcn_mfma_f32_16x16x32_bf16(af[mt], bfr[nt], acc[mt][nt], 0, 0, 0);
    cur = (cur == 2) ? 0 : cur + 1;
    pre = (pre == 2) ? 0 : pre + 1;
  }

#pragma unroll
  for (int mt = 0; mt < 4; ++mt) {
#pragma unroll
    for (int r = 0; r < 4; ++r) {
      const int gm = m_base + wm * 64 + mt * 16 + quad * 4 + r;
      if (gm < n_e) {
        bf16_t* orow = y + (size_t)(off + gm) * HD;
#pragma unroll
        for (int nt = 0; nt < 4; ++nt) {
          const int gh = n_base + wn * 64 + nt * 16 + lrow;
          orow[gh] = (bf16_t)(acc[mt][nt][r] + b2[e * HD + gh]);  // plain store
        }
      }
    }
  }
}

// ---------------- combine: out[t] = w1*y[p1] + w2*y[p2] ----
__global__ __launch_bounds__(256) void combine_kernel(const bf16_t* __restrict__ y,
                                                      const int* __restrict__ pos_of,
                                                      const float* __restrict__ tok_w,
                                                      float* __restrict__ out) {
  const int gid = blockIdx.x * 256 + threadIdx.x;
  const int t = gid >> 7;             // 128 8-wide chunks per token row
  const int c8 = (gid & 127) * 8;
  const int p1 = pos_of[2 * t];
  const int p2 = pos_of[2 * t + 1];
  const float w1 = tok_w[2 * t];
  const float w2 = tok_w[2 * t + 1];
  const bf16x8 a = *(const bf16x8*)(y + (size_t)p1 * HD + c8);
  const bf16x8 b = *(const bf16x8*)(y + (size_t)p2 * HD + c8);
  float* op = out + (size_t)t * HD + c8;
#pragma unroll
  for (int j = 0; j < 8; ++j) op[j] = w1 * (float)a[j] + w2 * (float)b[j];
}

extern "C" void kernel_launch(void* const* d_in, const int* in_sizes, int n_in,
                              void* d_out, int out_size, void* d_ws, size_t ws_size,
                              hipStream_t stream) {
  const float* x = (const float*)d_in[0];
  const float* Wg = (const float*)d_in[1];
  const float* W1 = (const float*)d_in[2];
  const float* b1 = (const float*)d_in[3];
  const float* W2 = (const float*)d_in[4];
  const float* b2 = (const float*)d_in[5];
  float* out = (float*)d_out;
  char* ws = (char*)d_ws;

  int* counts = (int*)(ws + WS_COUNTS);
  int* offsets = (int*)(ws + WS_OFFSETS);
  int* bucket_tok = (int*)(ws + WS_BTOK);
  float* bucket_w = (float*)(ws + WS_BW);
  int* tok_e = (int*)(ws + WS_TE);
  float* tok_w = (float*)(ws + WS_TW);
  int* wl_e = (int*)(ws + WS_WL);
  int* wl_m = wl_e + MAXWL;
  int* n_work = wl_m + MAXWL;
  int* blk_cnt = (int*)(ws + WS_BLKC);
  int* blk_base = (int*)(ws + WS_BLKB);
  int* pos_of = (int*)(ws + WS_POS);
  bf16_t* xb = (bf16_t*)(ws + WS_XB);
  bf16_t* h1 = (bf16_t*)(ws + WS_H1);
  bf16_t* WT = (bf16_t*)(ws + WS_WT);
  bf16_t* y = (bf16_t*)(ws + WS_Y);

  gate_kernel<<<TOKS / 8, 256, 0, stream>>>(x, Wg, xb, tok_e, tok_w);
  hist_kernel<<<TOKS * 2 / 256, 256, 0, stream>>>(tok_e, blk_cnt);
  scan_kernel<<<1, 64, 0, stream>>>(blk_cnt, counts, offsets, blk_base, wl_e, wl_m, n_work);
  scatter_kernel<<<TOKS * 2 / 256, 256, 0, stream>>>(tok_e, tok_w, blk_base, bucket_tok,
                                                     bucket_w, pos_of);
  transpose_convert_kernel<<<dim3(HD / 64, ID / 64, NE), 256, 0, stream>>>(W1, WT, HD, ID);
  gemm1_kernel<<<dim3(MAXWL, ID / 128), 256, 0, stream>>>(xb, WT, b1, counts, offsets, bucket_tok,
                                                          wl_e, wl_m, n_work, h1);
  transpose_convert_kernel<<<dim3(ID / 64, HD / 64, NE), 256, 0, stream>>>(W2, WT, ID, HD);
  gemm2_kernel<<<dim3(MAXWL, HD / 128), 256, 0, stream>>>(h1, WT, b2, counts, offsets, wl_e,
                                                          wl_m, n_work, y);
  combine_kernel<<<TOKS * HD / (256 * 8), 256, 0, stream>>>(y, pos_of, tok_w, out);
}

// Round 11
// 447.793 us; speedup vs baseline: 1.4485x; 1.0477x over previous
//
#include <hip/hip_runtime.h>
#include <math.h>

#define TOKS 8192
#define HD 1024
#define ID 2048
#define NE 8

typedef __bf16 bf16_t;
typedef __bf16 bf16x8 __attribute__((ext_vector_type(8)));
typedef float f32x4 __attribute__((ext_vector_type(4)));

// async global->LDS, 16 bytes per lane. LDS dest: wave-uniform base + lane*16.
#define GLOAD(gp, lp)                                                \
  __builtin_amdgcn_global_load_lds(                                  \
      (const __attribute__((address_space(1))) void*)(gp),           \
      (__attribute__((address_space(3))) void*)(lp), 16, 0, 0)

#define WAITV(N) asm volatile("s_waitcnt vmcnt(" #N ")" ::: "memory")
#define WAITL0() asm volatile("s_waitcnt lgkmcnt(0)" ::: "memory")

// branch-free erf-GELU (A&S 7.1.26, |eps|<=1.5e-7 — invisible under bf16 2^-9
// rounding; replaces branchy libm erff: epilogue VALU ~= whole K-loop MFMA).
__device__ __forceinline__ float gelu_exact(float v) {
  const float u = v * 0.70710678118654752f;
  const float a = fabsf(u);
  const float t = 1.f / (1.f + 0.3275911f * a);
  const float poly =
      t * (0.254829592f +
           t * (-0.284496736f +
                t * (1.421413741f + t * (-1.453152027f + t * 1.061405429f))));
  float er = 1.f - poly * __expf(-a * a);
  er = copysignf(er, u);
  return 0.5f * v * (1.f + er);
}

// ---------------- workspace layout (bytes) ----------------
#define WS_COUNTS 0
#define WS_OFFSETS 32
#define WS_BTOK 128
#define WS_BW (128 + 65536)
#define WS_TE (128 + 2 * 65536)
#define WS_TW (128 + 3 * 65536)
#define WS_WL 263168ull
#define WS_BLKC 266240ull                     // blk_cnt  [64][8] int
#define WS_BLKB 270336ull                     // blk_base [64][8] int
#define WS_POS 274432ull                      // pos_of   [16384] int (64 KB)
#define WS_XB 524288ull                       // bf16 x  [8192][1024]  = 16.78 MB
#define WS_H1 (WS_XB + 16777216ull)           // bf16 h1 [16384][2048] = 67.1 MB
#define WS_WT (WS_H1 + 67108864ull)           // bf16 WT (W1T then W2T) = 33.55 MB
#define WS_Y (WS_WT + 33554432ull)            // bf16 y  [16384][1024] = 33.55 MB (ends ~151.5 MB)

#define MAXWL 144
#define BM 128  // m-tile (rows of token bucket) — r5/r9-verified best geometry

// ---------------- gating + fused x->bf16 convert (r10-verified) ----------------
__global__ __launch_bounds__(256) void gate_kernel(const float* __restrict__ x,
                                                   const float* __restrict__ Wg,
                                                   bf16_t* __restrict__ xb,
                                                   int* __restrict__ tok_e,
                                                   float* __restrict__ tok_w) {
  __shared__ float WgT[NE][HD];  // 32 KB
  const int tid = threadIdx.x;
#pragma unroll
  for (int i = 0; i < NE * HD / 256; ++i) {
    const int idx = i * 256 + tid;
    WgT[idx & 7][idx >> 3] = Wg[idx];
  }
  __syncthreads();
  const int wv = tid >> 6;
  const int lane = tid & 63;
#pragma unroll
  for (int s = 0; s < 2; ++s) {
    const int t = blockIdx.x * 8 + wv * 2 + s;
    const float* xrow = x + (size_t)t * HD;
    bf16_t* xbrow = xb + (size_t)t * HD;
    float acc[NE];
#pragma unroll
    for (int e = 0; e < NE; ++e) acc[e] = 0.f;
#pragma unroll
    for (int i = 0; i < 16; ++i) {
      const int h = i * 64 + lane;
      const float xv = xrow[h];
      xbrow[h] = (bf16_t)xv;  // fused convert: 64 lanes x 2B = 128B contiguous
#pragma unroll
      for (int e = 0; e < NE; ++e) acc[e] += xv * WgT[e][h];
    }
#pragma unroll
    for (int off = 32; off >= 1; off >>= 1) {
#pragma unroll
      for (int e = 0; e < NE; ++e) acc[e] += __shfl_xor(acc[e], off);
    }
    if (lane == 0) {
      int i1 = 0;
      float l1 = acc[0];
#pragma unroll
      for (int e = 1; e < NE; ++e)
        if (acc[e] > l1) { l1 = acc[e]; i1 = e; }
      int i2 = -1;
      float l2 = -3.4e38f;
#pragma unroll
      for (int e = 0; e < NE; ++e)
        if (e != i1 && acc[e] > l2) { l2 = acc[e]; i2 = e; }
      const float q = expf(l2 - l1);
      const float w1 = 1.f / (1.f + q);
      tok_e[2 * t] = i1;
      tok_e[2 * t + 1] = i2;
      tok_w[2 * t] = w1;
      tok_w[2 * t + 1] = q * w1;
    }
  }
}

// ---------------- histogram: per-block per-expert counts via wave ballots ----
__global__ __launch_bounds__(256) void hist_kernel(const int* __restrict__ tok_e,
                                                   int* __restrict__ blk_cnt) {
  __shared__ int wcnt[4][NE];
  const int tid = threadIdx.x;
  const int idx = blockIdx.x * 256 + tid;
  const int e = tok_e[idx];
  const int w = tid >> 6;
  const int lane = tid & 63;
#pragma unroll
  for (int e0 = 0; e0 < NE; ++e0) {
    const unsigned long long m = __ballot(e == e0);
    if (lane == 0) wcnt[w][e0] = __popcll(m);
  }
  __syncthreads();
  if (tid < NE)
    blk_cnt[blockIdx.x * NE + tid] =
        wcnt[0][tid] + wcnt[1][tid] + wcnt[2][tid] + wcnt[3][tid];
}

// ---------------- scan: one wave; 64-wide shfl prefix-sum per expert ----
__global__ void scan_kernel(const int* __restrict__ blk_cnt, int* __restrict__ counts,
                            int* __restrict__ offsets, int* __restrict__ blk_base,
                            int* __restrict__ wl_e, int* __restrict__ wl_m,
                            int* __restrict__ n_work) {
  const int b = threadIdx.x;  // 0..63, one per scatter block
  int c[NE], pre[NE], tot[NE];
#pragma unroll
  for (int e = 0; e < NE; ++e) c[e] = blk_cnt[b * NE + e];
#pragma unroll
  for (int e = 0; e < NE; ++e) {
    int v = c[e];
#pragma unroll
    for (int off = 1; off < 64; off <<= 1) {
      const int u = __shfl_up(v, off);
      if (b >= off) v += u;
    }
    pre[e] = v - c[e];          // exclusive prefix over blocks
    tot[e] = __shfl(v, 63);     // expert total
  }
  int off_[NE];
  int s = 0;
#pragma unroll
  for (int e = 0; e < NE; ++e) {
    off_[e] = s;
    s += tot[e];
  }
#pragma unroll
  for (int e = 0; e < NE; ++e) blk_base[b * NE + e] = off_[e] + pre[e];
  if (b == 0) {
    int idx = 0;
    for (int e = 0; e < NE; ++e) {
      counts[e] = tot[e];
      offsets[e] = off_[e];
      for (int m = 0; m < tot[e] && idx < MAXWL; m += BM) {
        wl_e[idx] = e;
        wl_m[idx] = m;
        ++idx;
      }
    }
    *n_work = idx;
  }
}

// ---------------- scatter: position = blk_base + wave prefix + ballot rank ----
__global__ __launch_bounds__(256) void scatter_kernel(const int* __restrict__ tok_e,
                                                      const float* __restrict__ tok_w,
                                                      const int* __restrict__ blk_base,
                                                      int* __restrict__ bucket_tok,
                                                      float* __restrict__ bucket_w,
                                                      int* __restrict__ pos_of) {
  __shared__ int wcnt[4][NE];
  const int tid = threadIdx.x;
  const int idx = blockIdx.x * 256 + tid;
  const int e = tok_e[idx];
  const int w = tid >> 6;
  const int lane = tid & 63;
  unsigned long long mym = 0;
#pragma unroll
  for (int e0 = 0; e0 < NE; ++e0) {
    const unsigned long long m = __ballot(e == e0);
    if (lane == 0) wcnt[w][e0] = __popcll(m);
    if (e0 == e) mym = m;
  }
  __syncthreads();
  int base = blk_base[blockIdx.x * NE + e];
  for (int w2 = 0; w2 < w; ++w2) base += wcnt[w2][e];
  const int rank = __popcll(mym & ((1ull << lane) - 1ull));
  const int pos = base + rank;
  bucket_tok[pos] = idx >> 1;
  bucket_w[pos] = tok_w[idx];
  pos_of[idx] = pos;
}

// ---------------- transpose+convert: src [E][K][N] f32 -> dst [E][N][K] bf16 ----
// r11: global reads vectorized to float4 (were 4B/lane scalar — G13).
// tile stays [64][65]: 65-pad keeps the out-phase column reads 2-way on banks
// (68-pad would be 8-way); LDS writes split to b32 by alignment — cheap.
__global__ __launch_bounds__(256) void transpose_convert_kernel(const float* __restrict__ src,
                                                                bf16_t* __restrict__ dst, int K,
                                                                int N) {
  __shared__ float tile[64][65];
  const int e = blockIdx.z;
  const int k0 = blockIdx.x * 64;
  const int n0 = blockIdx.y * 64;
  const float* s = src + (size_t)e * K * N;
  bf16_t* d = dst + (size_t)e * K * N;
  const int t = threadIdx.x;
  const int c4 = (t & 15) * 4;
  const int rr = t >> 4;  // 0..15
#pragma unroll
  for (int p = 0; p < 4; ++p) {
    const int r = p * 16 + rr;
    const float4 v = *(const float4*)(s + (size_t)(k0 + r) * N + n0 + c4);
    tile[r][c4] = v.x;
    tile[r][c4 + 1] = v.y;
    tile[r][c4 + 2] = v.z;
    tile[r][c4 + 3] = v.w;
  }
  __syncthreads();
  const int kc = t & 7;
  const int nb = t >> 3;
#pragma unroll
  for (int p = 0; p < 2; ++p) {
    const int n = p * 32 + nb;
    bf16_t o[8];
#pragma unroll
    for (int j = 0; j < 8; ++j) o[j] = (bf16_t)tile[kc * 8 + j][n];
    *(uint4*)(d + (size_t)(n0 + n) * K + k0 + kc * 8) = *(uint4*)o;
  }
}

// ---------------- expert GEMMs: 128x128 tile, 3-buffer counted-vmcnt pipeline ----
// r10 post-mortem: 8.65M "conflicts" are 2-way aliasing at ds_read_b128's
// 8-lane phase granularity — counted but free (m136); both swizzle keys
// equivalent. Real epilogue costs attacked in r11:
// SWAPPED-OPERAND MFMA: mfma(bfr, af) computes C^T, so D row = n (quad*4+r),
// D col = token (lrow). Each lane then owns 4 CONSECUTIVE output columns per
// (mt,nt) -> 16x 8B stores replace 64x 2B scalar stores; bias loads become
// float4. Staging/swizzle/pipeline identical to r9/r10 (verified).

__global__ __launch_bounds__(256, 3) void gemm1_kernel(
    const bf16_t* __restrict__ xb, const bf16_t* __restrict__ W1T, const float* __restrict__ b1,
    const int* __restrict__ counts, const int* __restrict__ offsets,
    const int* __restrict__ bucket_tok, const int* __restrict__ wl_e,
    const int* __restrict__ wl_m, const int* __restrict__ n_work, bf16_t* __restrict__ h1) {
  const int widx = blockIdx.x;
  if (widx >= *n_work) return;
  const int e = wl_e[widx];
  const int m_base = wl_m[widx];
  const int n_e = counts[e];
  const int n_base = blockIdx.y * 128;
  const int off = offsets[e];

  __shared__ bf16_t As[3][128 * 32];  // 8 KB each
  __shared__ bf16_t Bs[3][128 * 32];

  const int tid = threadIdx.x;
  const int w = tid >> 6;
  const int lane = tid & 63;
  const int quad = lane >> 4;
  const int lrow = lane & 15;
  const int wm = w >> 1;   // 64-row half
  const int wn = w & 1;    // 64-col half

  const int srow = lane >> 2;                        // 16 rows per GLOAD
  const int kch = (((lane & 3) ^ ((lane >> 4) & 3)) * 8);  // pre-swizzled source chunk
  int r0 = m_base + w * 32 + srow;
  int r1 = r0 + 16;
  if (r0 >= n_e) r0 = n_e - 1;
  if (r1 >= n_e) r1 = n_e - 1;
  const bf16_t* ga0 = xb + (size_t)bucket_tok[off + r0] * HD + kch;
  const bf16_t* ga1 = xb + (size_t)bucket_tok[off + r1] * HD + kch;
  const bf16_t* gb0 = W1T + ((size_t)e * ID + n_base + w * 32 + srow) * HD + kch;
  const bf16_t* gb1 = gb0 + (size_t)16 * HD;
  const int laofs0 = w * 1024 + lane * 8;  // rows w*32.. in [128][32]
  const int laofs1 = laofs0 + 512;         // +16 rows

  f32x4 acc[4][4];
#pragma unroll
  for (int mt = 0; mt < 4; ++mt)
#pragma unroll
    for (int nt = 0; nt < 4; ++nt)
#pragma unroll
      for (int r = 0; r < 4; ++r) acc[mt][nt][r] = 0.f;

  // prologue: stage tiles 0 and 1 (8 outstanding GLOADs/wave)
#pragma unroll
  for (int p = 0; p < 2; ++p) {
    const size_t ko = (size_t)p * 32;
    GLOAD(ga0 + ko, &As[p][laofs0]);
    GLOAD(ga1 + ko, &As[p][laofs1]);
    GLOAD(gb0 + ko, &Bs[p][laofs0]);
    GLOAD(gb1 + ko, &Bs[p][laofs1]);
  }

  const int slot = (quad ^ ((lrow >> 2) & 3)) * 8;
  int cur = 0;        // kt % 3, carried (no div in loop)
  int pre = 2;        // (kt+2) % 3, carried
#define NT1 (HD / 32)
  for (int kt = 0; kt < NT1; ++kt) {
    WAITL0();                          // prior iter's ds_reads done (per-wave)
    __builtin_amdgcn_s_barrier();      // #1: buf[(kt+2)%3] free to overwrite
    if (kt + 2 < NT1) {
      const size_t ko = (size_t)(kt + 2) * 32;
      GLOAD(ga0 + ko, &As[pre][laofs0]);
      GLOAD(ga1 + ko, &As[pre][laofs1]);
      GLOAD(gb0 + ko, &Bs[pre][laofs0]);
      GLOAD(gb1 + ko, &Bs[pre][laofs1]);
      WAITV(8);                        // tile kt landed; kt+1,kt+2 in flight
    } else if (kt + 1 < NT1) {
      WAITV(4);
    } else {
      WAITV(0);
    }
    __builtin_amdgcn_s_barrier();      // #2: tile kt visible to all waves
    __builtin_amdgcn_sched_barrier(0); // fence: no ds_read hoists above
    bf16x8 af[4], bfr[4];
#pragma unroll
    for (int i = 0; i < 4; ++i) {
      af[i] = *(const bf16x8*)(&As[cur][(wm * 64 + i * 16 + lrow) * 32 + slot]);
      bfr[i] = *(const bf16x8*)(&Bs[cur][(wn * 64 + i * 16 + lrow) * 32 + slot]);
    }
#pragma unroll
    for (int mt = 0; mt < 4; ++mt)
#pragma unroll
      for (int nt = 0; nt < 4; ++nt)
        acc[mt][nt] =
            __builtin_amdgcn_mfma_f32_16x16x32_bf16(bfr[nt], af[mt], acc[mt][nt], 0, 0, 0);
    cur = (cur == 2) ? 0 : cur + 1;
    pre = (pre == 2) ? 0 : pre + 1;
  }

  // C^T epilogue: lane owns token gm = ..+lrow; 4 consecutive cols per (nt).
#pragma unroll
  for (int mt = 0; mt < 4; ++mt) {
    const int gm = m_base + wm * 64 + mt * 16 + lrow;
    if (gm < n_e) {
      bf16_t* orow = h1 + (size_t)(off + gm) * ID;
#pragma unroll
      for (int nt = 0; nt < 4; ++nt) {
        const int gi0 = n_base + wn * 64 + nt * 16 + quad * 4;
        const float4 bb = *(const float4*)(b1 + e * ID + gi0);
        const float bv[4] = {bb.x, bb.y, bb.z, bb.w};
        bf16_t o[4];
#pragma unroll
        for (int r = 0; r < 4; ++r) o[r] = (bf16_t)gelu_exact(acc[mt][nt][r] + bv[r]);
        *(uint2*)(orow + gi0) = *(uint2*)o;
      }
    }
  }
}

// gemm2: identical loop; epilogue stores y[pos] = row + b2 (bf16, NO atomics;
// r9-verified). Combine applies gate weights and writes out once.
__global__ __launch_bounds__(256, 3) void gemm2_kernel(
    const bf16_t* __restrict__ h1, const bf16_t* __restrict__ W2T, const float* __restrict__ b2,
    const int* __restrict__ counts, const int* __restrict__ offsets,
    const int* __restrict__ wl_e, const int* __restrict__ wl_m, const int* __restrict__ n_work,
    bf16_t* __restrict__ y) {
  const int widx = blockIdx.x;
  if (widx >= *n_work) return;
  const int e = wl_e[widx];
  const int m_base = wl_m[widx];
  const int n_e = counts[e];
  const int n_base = blockIdx.y * 128;
  const int off = offsets[e];

  __shared__ bf16_t As[3][128 * 32];
  __shared__ bf16_t Bs[3][128 * 32];

  const int tid = threadIdx.x;
  const int w = tid >> 6;
  const int lane = tid & 63;
  const int quad = lane >> 4;
  const int lrow = lane & 15;
  const int wm = w >> 1;
  const int wn = w & 1;

  const int srow = lane >> 2;
  const int kch = (((lane & 3) ^ ((lane >> 4) & 3)) * 8);
  int r0 = m_base + w * 32 + srow;
  int r1 = r0 + 16;
  if (r0 >= n_e) r0 = n_e - 1;
  if (r1 >= n_e) r1 = n_e - 1;
  const bf16_t* ga0 = h1 + (size_t)(off + r0) * ID + kch;
  const bf16_t* ga1 = h1 + (size_t)(off + r1) * ID + kch;
  const bf16_t* gb0 = W2T + ((size_t)e * HD + n_base + w * 32 + srow) * ID + kch;
  const bf16_t* gb1 = gb0 + (size_t)16 * ID;
  const int laofs0 = w * 1024 + lane * 8;
  const int laofs1 = laofs0 + 512;

  f32x4 acc[4][4];
#pragma unroll
  for (int mt = 0; mt < 4; ++mt)
#pragma unroll
    for (int nt = 0; nt < 4; ++nt)
#pragma unroll
      for (int r = 0; r < 4; ++r) acc[mt][nt][r] = 0.f;

#pragma unroll
  for (int p = 0; p < 2; ++p) {
    const size_t ko = (size_t)p * 32;
    GLOAD(ga0 + ko, &As[p][laofs0]);
    GLOAD(ga1 + ko, &As[p][laofs1]);
    GLOAD(gb0 + ko, &Bs[p][laofs0]);
    GLOAD(gb1 + ko, &Bs[p][laofs1]);
  }

  const int slot = (quad ^ ((lrow >> 2) & 3)) * 8;
  int cur = 0;
  int pre = 2;
#define NT2 (ID / 32)
  for (int kt = 0; kt < NT2; ++kt) {
    WAITL0();
    __builtin_amdgcn_s_barrier();
    if (kt + 2 < NT2) {
      const size_t ko = (size_t)(kt + 2) * 32;
      GLOAD(ga0 + ko, &As[pre][laofs0]);
      GLOAD(ga1 + ko, &As[pre][laofs1]);
      GLOAD(gb0 + ko, &Bs[pre][laofs0]);
      GLOAD(gb1 + ko, &Bs[pre][laofs1]);
      WAITV(8);
    } else if (kt + 1 < NT2) {
      WAITV(4);
    } else {
      WAITV(0);
    }
    __builtin_amdgcn_s_barrier();
    __builtin_amdgcn_sched_barrier(0);
    bf16x8 af[4], bfr[4];
#pragma unroll
    for (int i = 0; i < 4; ++i) {
      af[i] = *(const bf16x8*)(&As[cur][(wm * 64 + i * 16 + lrow) * 32 + slot]);
      bfr[i] = *(const bf16x8*)(&Bs[cur][(wn * 64 + i * 16 + lrow) * 32 + slot]);
    }
#pragma unroll
    for (int mt = 0; mt < 4; ++mt)
#pragma unroll
      for (int nt = 0; nt < 4; ++nt)
        acc[mt][nt] =
            __builtin_amdgcn_mfma_f32_16x16x32_bf16(bfr[nt], af[mt], acc[mt][nt], 0, 0, 0);
    cur = (cur == 2) ? 0 : cur + 1;
    pre = (pre == 2) ? 0 : pre + 1;
  }

#pragma unroll
  for (int mt = 0; mt < 4; ++mt) {
    const int gm = m_base + wm * 64 + mt * 16 + lrow;
    if (gm < n_e) {
      bf16_t* orow = y + (size_t)(off + gm) * HD;
#pragma unroll
      for (int nt = 0; nt < 4; ++nt) {
        const int gi0 = n_base + wn * 64 + nt * 16 + quad * 4;
        const float4 bb = *(const float4*)(b2 + e * HD + gi0);
        const float bv[4] = {bb.x, bb.y, bb.z, bb.w};
        bf16_t o[4];
#pragma unroll
        for (int r = 0; r < 4; ++r) o[r] = (bf16_t)(acc[mt][nt][r] + bv[r]);
        *(uint2*)(orow + gi0) = *(uint2*)o;
      }
    }
  }
}

// ---------------- combine: out[t] = w1*y[p1] + w2*y[p2] ----
__global__ __launch_bounds__(256) void combine_kernel(const bf16_t* __restrict__ y,
                                                      const int* __restrict__ pos_of,
                                                      const float* __restrict__ tok_w,
                                                      float* __restrict__ out) {
  const int gid = blockIdx.x * 256 + threadIdx.x;
  const int t = gid >> 7;             // 128 8-wide chunks per token row
  const int c8 = (gid & 127) * 8;
  const int p1 = pos_of[2 * t];
  const int p2 = pos_of[2 * t + 1];
  const float w1 = tok_w[2 * t];
  const float w2 = tok_w[2 * t + 1];
  const bf16x8 a = *(const bf16x8*)(y + (size_t)p1 * HD + c8);
  const bf16x8 b = *(const bf16x8*)(y + (size_t)p2 * HD + c8);
  float* op = out + (size_t)t * HD + c8;
  float ov[8];
#pragma unroll
  for (int j = 0; j < 8; ++j) ov[j] = w1 * (float)a[j] + w2 * (float)b[j];
  *(float4*)op = make_float4(ov[0], ov[1], ov[2], ov[3]);
  *(float4*)(op + 4) = make_float4(ov[4], ov[5], ov[6], ov[7]);
}

extern "C" void kernel_launch(void* const* d_in, const int* in_sizes, int n_in,
                              void* d_out, int out_size, void* d_ws, size_t ws_size,
                              hipStream_t stream) {
  const float* x = (const float*)d_in[0];
  const float* Wg = (const float*)d_in[1];
  const float* W1 = (const float*)d_in[2];
  const float* b1 = (const float*)d_in[3];
  const float* W2 = (const float*)d_in[4];
  const float* b2 = (const float*)d_in[5];
  float* out = (float*)d_out;
  char* ws = (char*)d_ws;

  int* counts = (int*)(ws + WS_COUNTS);
  int* offsets = (int*)(ws + WS_OFFSETS);
  int* bucket_tok = (int*)(ws + WS_BTOK);
  float* bucket_w = (float*)(ws + WS_BW);
  int* tok_e = (int*)(ws + WS_TE);
  float* tok_w = (float*)(ws + WS_TW);
  int* wl_e = (int*)(ws + WS_WL);
  int* wl_m = wl_e + MAXWL;
  int* n_work = wl_m + MAXWL;
  int* blk_cnt = (int*)(ws + WS_BLKC);
  int* blk_base = (int*)(ws + WS_BLKB);
  int* pos_of = (int*)(ws + WS_POS);
  bf16_t* xb = (bf16_t*)(ws + WS_XB);
  bf16_t* h1 = (bf16_t*)(ws + WS_H1);
  bf16_t* WT = (bf16_t*)(ws + WS_WT);
  bf16_t* y = (bf16_t*)(ws + WS_Y);

  gate_kernel<<<TOKS / 8, 256, 0, stream>>>(x, Wg, xb, tok_e, tok_w);
  hist_kernel<<<TOKS * 2 / 256, 256, 0, stream>>>(tok_e, blk_cnt);
  scan_kernel<<<1, 64, 0, stream>>>(blk_cnt, counts, offsets, blk_base, wl_e, wl_m, n_work);
  scatter_kernel<<<TOKS * 2 / 256, 256, 0, stream>>>(tok_e, tok_w, blk_base, bucket_tok,
                                                     bucket_w, pos_of);
  transpose_convert_kernel<<<dim3(HD / 64, ID / 64, NE), 256, 0, stream>>>(W1, WT, HD, ID);
  gemm1_kernel<<<dim3(MAXWL, ID / 128), 256, 0, stream>>>(xb, WT, b1, counts, offsets, bucket_tok,
                                                          wl_e, wl_m, n_work, h1);
  transpose_convert_kernel<<<dim3(ID / 64, HD / 64, NE), 256, 0, stream>>>(W2, WT, ID, HD);
  gemm2_kernel<<<dim3(MAXWL, HD / 128), 256, 0, stream>>>(h1, WT, b2, counts, offsets, wl_e,
                                                          wl_m, n_work, y);
  combine_kernel<<<TOKS * HD / (256 * 8), 256, 0, stream>>>(y, pos_of, tok_w, out);
}

// Round 12
// 447.373 us; speedup vs baseline: 1.4498x; 1.0009x over previous
//
#include <hip/hip_runtime.h>
#include <math.h>

#define TOKS 8192
#define HD 1024
#define ID 2048
#define NE 8

typedef __bf16 bf16_t;
typedef __bf16 bf16x8 __attribute__((ext_vector_type(8)));
typedef float f32x4 __attribute__((ext_vector_type(4)));

// async global->LDS, 16 bytes per lane. LDS dest: wave-uniform base + lane*16.
#define GLOAD(gp, lp)                                                \
  __builtin_amdgcn_global_load_lds(                                  \
      (const __attribute__((address_space(1))) void*)(gp),           \
      (__attribute__((address_space(3))) void*)(lp), 16, 0, 0)

#define WAITV(N) asm volatile("s_waitcnt vmcnt(" #N ")" ::: "memory")
#define WAITL0() asm volatile("s_waitcnt lgkmcnt(0)" ::: "memory")

// branch-free erf-GELU (A&S 7.1.26, |eps|<=1.5e-7 — invisible under bf16 2^-9
// rounding). r11-verified: absmax unchanged vs libm erff.
__device__ __forceinline__ float gelu_exact(float v) {
  const float u = v * 0.70710678118654752f;
  const float a = fabsf(u);
  const float t = 1.f / (1.f + 0.3275911f * a);
  const float poly =
      t * (0.254829592f +
           t * (-0.284496736f +
                t * (1.421413741f + t * (-1.453152027f + t * 1.061405429f))));
  float er = 1.f - poly * __expf(-a * a);
  er = copysignf(er, u);
  return 0.5f * v * (1.f + er);
}

// ---------------- workspace layout (bytes) ----------------
#define WS_COUNTS 0
#define WS_OFFSETS 32
#define WS_BTOK 128
#define WS_BW (128 + 65536)
#define WS_TE (128 + 2 * 65536)
#define WS_TW (128 + 3 * 65536)
#define WS_WL 263168ull
#define WS_POS 274432ull                      // pos_of   [16384] int (64 KB)
#define WS_RANK 339968ull                     // rank_of  [16384] int (64 KB)
#define WS_BLKC 405504ull                     // blk_cnt  [1024][8] int (32 KB)
#define WS_BLKB 438272ull                     // blk_base [1024][8] int (32 KB)
#define WS_XB 524288ull                       // bf16 x  [8192][1024]  = 16.78 MB
#define WS_H1 (WS_XB + 16777216ull)           // bf16 h1 [16384][2048] = 67.1 MB
#define WS_WT (WS_H1 + 67108864ull)           // bf16 WT (W1T then W2T) = 33.55 MB
#define WS_Y (WS_WT + 33554432ull)            // bf16 y  [16384][1024] = 33.55 MB (ends ~151.5 MB)

#define MAXWL 144
#define BM 128  // m-tile (rows of token bucket) — r5/r9-verified best geometry
#define GB (TOKS / 8)  // gate blocks = 1024

// ---------------- gating + fused convert + fused histogram ----------------
// r12: (a) Wg's native [H][E] layout already gives per-lane 8-consecutive
// weights — no transpose; weight row read as 2x ds_read_b128 (2-way bank
// aliasing = free, m136) instead of 8x b32: ~2x fewer LDS cycles.
// (b) hist fused: LDS atomicAdd per pick captures within-block rank (16
// adds/block, no contention); block writes blk_cnt[1024][8]. Rank order is
// nondeterministic but positions stay unique; pos_of keeps combine exact.
__global__ __launch_bounds__(256) void gate_kernel(const float* __restrict__ x,
                                                   const float* __restrict__ Wg,
                                                   bf16_t* __restrict__ xb,
                                                   int* __restrict__ tok_e,
                                                   float* __restrict__ tok_w,
                                                   int* __restrict__ rank_of,
                                                   int* __restrict__ blk_cnt) {
  __shared__ float WgT[HD * NE];  // straight copy of Wg (32 KB)
  __shared__ int cnt[NE];
  const int tid = threadIdx.x;
#pragma unroll
  for (int i = 0; i < NE * HD / (256 * 4); ++i) {  // 8 float4 per thread
    const int k = i * 256 + tid;
    ((float4*)WgT)[k] = ((const float4*)Wg)[k];
  }
  if (tid < NE) cnt[tid] = 0;
  __syncthreads();
  const int wv = tid >> 6;
  const int lane = tid & 63;
#pragma unroll
  for (int s = 0; s < 2; ++s) {
    const int t = blockIdx.x * 8 + wv * 2 + s;
    const float* xrow = x + (size_t)t * HD;
    bf16_t* xbrow = xb + (size_t)t * HD;
    float acc[NE];
#pragma unroll
    for (int e = 0; e < NE; ++e) acc[e] = 0.f;
#pragma unroll
    for (int i = 0; i < 16; ++i) {
      const int h = i * 64 + lane;
      const float xv = xrow[h];
      xbrow[h] = (bf16_t)xv;  // fused convert: 64 lanes x 2B = 128B contiguous
      const float4 w0 = *(const float4*)(WgT + h * NE);
      const float4 w1 = *(const float4*)(WgT + h * NE + 4);
      acc[0] += xv * w0.x;
      acc[1] += xv * w0.y;
      acc[2] += xv * w0.z;
      acc[3] += xv * w0.w;
      acc[4] += xv * w1.x;
      acc[5] += xv * w1.y;
      acc[6] += xv * w1.z;
      acc[7] += xv * w1.w;
    }
#pragma unroll
    for (int off = 32; off >= 1; off >>= 1) {
#pragma unroll
      for (int e = 0; e < NE; ++e) acc[e] += __shfl_xor(acc[e], off);
    }
    if (lane == 0) {
      int i1 = 0;
      float l1 = acc[0];
#pragma unroll
      for (int e = 1; e < NE; ++e)
        if (acc[e] > l1) { l1 = acc[e]; i1 = e; }
      int i2 = -1;
      float l2 = -3.4e38f;
#pragma unroll
      for (int e = 0; e < NE; ++e)
        if (e != i1 && acc[e] > l2) { l2 = acc[e]; i2 = e; }
      const float q = expf(l2 - l1);
      const float w1 = 1.f / (1.f + q);
      tok_e[2 * t] = i1;
      tok_e[2 * t + 1] = i2;
      tok_w[2 * t] = w1;
      tok_w[2 * t + 1] = q * w1;
      rank_of[2 * t] = atomicAdd(&cnt[i1], 1);      // LDS atomic: rank in block
      rank_of[2 * t + 1] = atomicAdd(&cnt[i2], 1);
    }
  }
  __syncthreads();
  if (tid < NE) blk_cnt[blockIdx.x * NE + tid] = cnt[tid];
}

// ---------------- scan: one wave; 16 gate-blocks per lane + 64-wide prefix ----
__global__ void scan_kernel(const int* __restrict__ blk_cnt, int* __restrict__ counts,
                            int* __restrict__ offsets, int* __restrict__ blk_base,
                            int* __restrict__ wl_e, int* __restrict__ wl_m,
                            int* __restrict__ n_work) {
  const int b = threadIdx.x;  // 0..63; handles gate-blocks b*16 .. b*16+15
  int sum[NE], pre[NE], tot[NE];
#pragma unroll
  for (int e = 0; e < NE; ++e) {
    int s = 0;
    for (int j = 0; j < 16; ++j) s += blk_cnt[(b * 16 + j) * NE + e];
    sum[e] = s;
  }
#pragma unroll
  for (int e = 0; e < NE; ++e) {
    int v = sum[e];
#pragma unroll
    for (int off = 1; off < 64; off <<= 1) {
      const int u = __shfl_up(v, off);
      if (b >= off) v += u;
    }
    pre[e] = v - sum[e];        // exclusive prefix over lanes
    tot[e] = __shfl(v, 63);     // expert total
  }
  int off_[NE];
  int s = 0;
#pragma unroll
  for (int e = 0; e < NE; ++e) {
    off_[e] = s;
    s += tot[e];
  }
#pragma unroll
  for (int e = 0; e < NE; ++e) {
    int run = off_[e] + pre[e];
    for (int j = 0; j < 16; ++j) {
      blk_base[(b * 16 + j) * NE + e] = run;
      run += blk_cnt[(b * 16 + j) * NE + e];
    }
  }
  if (b == 0) {
    int idx = 0;
    for (int e = 0; e < NE; ++e) {
      counts[e] = tot[e];
      offsets[e] = off_[e];
      for (int m = 0; m < tot[e] && idx < MAXWL; m += BM) {
        wl_e[idx] = e;
        wl_m[idx] = m;
        ++idx;
      }
    }
    *n_work = idx;
  }
}

// ---------------- scatter: pure gather now — pos = blk_base + rank ----
__global__ __launch_bounds__(256) void scatter_kernel(const int* __restrict__ tok_e,
                                                      const float* __restrict__ tok_w,
                                                      const int* __restrict__ blk_base,
                                                      const int* __restrict__ rank_of,
                                                      int* __restrict__ bucket_tok,
                                                      float* __restrict__ bucket_w,
                                                      int* __restrict__ pos_of) {
  const int idx = blockIdx.x * 256 + threadIdx.x;
  const int e = tok_e[idx];
  const int gb = idx >> 4;  // 16 picks per gate-block
  const int pos = blk_base[gb * NE + e] + rank_of[idx];
  bucket_tok[pos] = idx >> 1;
  bucket_w[pos] = tok_w[idx];
  pos_of[idx] = pos;
}

// ---------------- transpose+convert: src [E][K][N] f32 -> dst [E][N][K] bf16 ----
// r11-verified: float4 global reads; [64][65] tile keeps out-phase 2-way.
__global__ __launch_bounds__(256) void transpose_convert_kernel(const float* __restrict__ src,
                                                                bf16_t* __restrict__ dst, int K,
                                                                int N) {
  __shared__ float tile[64][65];
  const int e = blockIdx.z;
  const int k0 = blockIdx.x * 64;
  const int n0 = blockIdx.y * 64;
  const float* s = src + (size_t)e * K * N;
  bf16_t* d = dst + (size_t)e * K * N;
  const int t = threadIdx.x;
  const int c4 = (t & 15) * 4;
  const int rr = t >> 4;  // 0..15
#pragma unroll
  for (int p = 0; p < 4; ++p) {
    const int r = p * 16 + rr;
    const float4 v = *(const float4*)(s + (size_t)(k0 + r) * N + n0 + c4);
    tile[r][c4] = v.x;
    tile[r][c4 + 1] = v.y;
    tile[r][c4 + 2] = v.z;
    tile[r][c4 + 3] = v.w;
  }
  __syncthreads();
  const int kc = t & 7;
  const int nb = t >> 3;
#pragma unroll
  for (int p = 0; p < 2; ++p) {
    const int n = p * 32 + nb;
    bf16_t o[8];
#pragma unroll
    for (int j = 0; j < 8; ++j) o[j] = (bf16_t)tile[kc * 8 + j][n];
    *(uint4*)(d + (size_t)(n0 + n) * K + k0 + kc * 8) = *(uint4*)o;
  }
}

// ---------------- expert GEMMs: 128x128 tile, 3-buffer counted-vmcnt pipeline ----
// r12: + T5 s_setprio(1) around the MFMA cluster. m190's null was 4-wave
// LOCKSTEP (1 block); here 3 independent blocks/CU sit at staggered phases —
// the role-diversity regime where setprio paid +4-7% (m191 attn analog).
// Swapped-operand MFMA (r11-verified): mfma(bfr, af) = C^T; lane owns token
// row, writes 4 consecutive cols per fragment (uint2).

__global__ __launch_bounds__(256, 3) void gemm1_kernel(
    const bf16_t* __restrict__ xb, const bf16_t* __restrict__ W1T, const float* __restrict__ b1,
    const int* __restrict__ counts, const int* __restrict__ offsets,
    const int* __restrict__ bucket_tok, const int* __restrict__ wl_e,
    const int* __restrict__ wl_m, const int* __restrict__ n_work, bf16_t* __restrict__ h1) {
  const int widx = blockIdx.x;
  if (widx >= *n_work) return;
  const int e = wl_e[widx];
  const int m_base = wl_m[widx];
  const int n_e = counts[e];
  const int n_base = blockIdx.y * 128;
  const int off = offsets[e];

  __shared__ bf16_t As[3][128 * 32];  // 8 KB each
  __shared__ bf16_t Bs[3][128 * 32];

  const int tid = threadIdx.x;
  const int w = tid >> 6;
  const int lane = tid & 63;
  const int quad = lane >> 4;
  const int lrow = lane & 15;
  const int wm = w >> 1;   // 64-row half
  const int wn = w & 1;    // 64-col half

  const int srow = lane >> 2;                        // 16 rows per GLOAD
  const int kch = (((lane & 3) ^ ((lane >> 4) & 3)) * 8);  // pre-swizzled source chunk
  int r0 = m_base + w * 32 + srow;
  int r1 = r0 + 16;
  if (r0 >= n_e) r0 = n_e - 1;
  if (r1 >= n_e) r1 = n_e - 1;
  const bf16_t* ga0 = xb + (size_t)bucket_tok[off + r0] * HD + kch;
  const bf16_t* ga1 = xb + (size_t)bucket_tok[off + r1] * HD + kch;
  const bf16_t* gb0 = W1T + ((size_t)e * ID + n_base + w * 32 + srow) * HD + kch;
  const bf16_t* gb1 = gb0 + (size_t)16 * HD;
  const int laofs0 = w * 1024 + lane * 8;  // rows w*32.. in [128][32]
  const int laofs1 = laofs0 + 512;         // +16 rows

  f32x4 acc[4][4];
#pragma unroll
  for (int mt = 0; mt < 4; ++mt)
#pragma unroll
    for (int nt = 0; nt < 4; ++nt)
#pragma unroll
      for (int r = 0; r < 4; ++r) acc[mt][nt][r] = 0.f;

  // prologue: stage tiles 0 and 1 (8 outstanding GLOADs/wave)
#pragma unroll
  for (int p = 0; p < 2; ++p) {
    const size_t ko = (size_t)p * 32;
    GLOAD(ga0 + ko, &As[p][laofs0]);
    GLOAD(ga1 + ko, &As[p][laofs1]);
    GLOAD(gb0 + ko, &Bs[p][laofs0]);
    GLOAD(gb1 + ko, &Bs[p][laofs1]);
  }

  const int slot = (quad ^ ((lrow >> 2) & 3)) * 8;
  int cur = 0;        // kt % 3, carried (no div in loop)
  int pre = 2;        // (kt+2) % 3, carried
#define NT1 (HD / 32)
  for (int kt = 0; kt < NT1; ++kt) {
    WAITL0();                          // prior iter's ds_reads done (per-wave)
    __builtin_amdgcn_s_barrier();      // #1: buf[(kt+2)%3] free to overwrite
    if (kt + 2 < NT1) {
      const size_t ko = (size_t)(kt + 2) * 32;
      GLOAD(ga0 + ko, &As[pre][laofs0]);
      GLOAD(ga1 + ko, &As[pre][laofs1]);
      GLOAD(gb0 + ko, &Bs[pre][laofs0]);
      GLOAD(gb1 + ko, &Bs[pre][laofs1]);
      WAITV(8);                        // tile kt landed; kt+1,kt+2 in flight
    } else if (kt + 1 < NT1) {
      WAITV(4);
    } else {
      WAITV(0);
    }
    __builtin_amdgcn_s_barrier();      // #2: tile kt visible to all waves
    __builtin_amdgcn_sched_barrier(0); // fence: no ds_read hoists above
    bf16x8 af[4], bfr[4];
#pragma unroll
    for (int i = 0; i < 4; ++i) {
      af[i] = *(const bf16x8*)(&As[cur][(wm * 64 + i * 16 + lrow) * 32 + slot]);
      bfr[i] = *(const bf16x8*)(&Bs[cur][(wn * 64 + i * 16 + lrow) * 32 + slot]);
    }
    __builtin_amdgcn_s_setprio(1);
#pragma unroll
    for (int mt = 0; mt < 4; ++mt)
#pragma unroll
      for (int nt = 0; nt < 4; ++nt)
        acc[mt][nt] =
            __builtin_amdgcn_mfma_f32_16x16x32_bf16(bfr[nt], af[mt], acc[mt][nt], 0, 0, 0);
    __builtin_amdgcn_s_setprio(0);
    cur = (cur == 2) ? 0 : cur + 1;
    pre = (pre == 2) ? 0 : pre + 1;
  }

  // C^T epilogue: lane owns token gm = ..+lrow; 4 consecutive cols per (nt).
#pragma unroll
  for (int mt = 0; mt < 4; ++mt) {
    const int gm = m_base + wm * 64 + mt * 16 + lrow;
    if (gm < n_e) {
      bf16_t* orow = h1 + (size_t)(off + gm) * ID;
#pragma unroll
      for (int nt = 0; nt < 4; ++nt) {
        const int gi0 = n_base + wn * 64 + nt * 16 + quad * 4;
        const float4 bb = *(const float4*)(b1 + e * ID + gi0);
        const float bv[4] = {bb.x, bb.y, bb.z, bb.w};
        bf16_t o[4];
#pragma unroll
        for (int r = 0; r < 4; ++r) o[r] = (bf16_t)gelu_exact(acc[mt][nt][r] + bv[r]);
        *(uint2*)(orow + gi0) = *(uint2*)o;
      }
    }
  }
}

// gemm2: identical loop; epilogue stores y[pos] = row + b2 (bf16, no atomics).
__global__ __launch_bounds__(256, 3) void gemm2_kernel(
    const bf16_t* __restrict__ h1, const bf16_t* __restrict__ W2T, const float* __restrict__ b2,
    const int* __restrict__ counts, const int* __restrict__ offsets,
    const int* __restrict__ wl_e, const int* __restrict__ wl_m, const int* __restrict__ n_work,
    bf16_t* __restrict__ y) {
  const int widx = blockIdx.x;
  if (widx >= *n_work) return;
  const int e = wl_e[widx];
  const int m_base = wl_m[widx];
  const int n_e = counts[e];
  const int n_base = blockIdx.y * 128;
  const int off = offsets[e];

  __shared__ bf16_t As[3][128 * 32];
  __shared__ bf16_t Bs[3][128 * 32];

  const int tid = threadIdx.x;
  const int w = tid >> 6;
  const int lane = tid & 63;
  const int quad = lane >> 4;
  const int lrow = lane & 15;
  const int wm = w >> 1;
  const int wn = w & 1;

  const int srow = lane >> 2;
  const int kch = (((lane & 3) ^ ((lane >> 4) & 3)) * 8);
  int r0 = m_base + w * 32 + srow;
  int r1 = r0 + 16;
  if (r0 >= n_e) r0 = n_e - 1;
  if (r1 >= n_e) r1 = n_e - 1;
  const bf16_t* ga0 = h1 + (size_t)(off + r0) * ID + kch;
  const bf16_t* ga1 = h1 + (size_t)(off + r1) * ID + kch;
  const bf16_t* gb0 = W2T + ((size_t)e * HD + n_base + w * 32 + srow) * ID + kch;
  const bf16_t* gb1 = gb0 + (size_t)16 * ID;
  const int laofs0 = w * 1024 + lane * 8;
  const int laofs1 = laofs0 + 512;

  f32x4 acc[4][4];
#pragma unroll
  for (int mt = 0; mt < 4; ++mt)
#pragma unroll
    for (int nt = 0; nt < 4; ++nt)
#pragma unroll
      for (int r = 0; r < 4; ++r) acc[mt][nt][r] = 0.f;

#pragma unroll
  for (int p = 0; p < 2; ++p) {
    const size_t ko = (size_t)p * 32;
    GLOAD(ga0 + ko, &As[p][laofs0]);
    GLOAD(ga1 + ko, &As[p][laofs1]);
    GLOAD(gb0 + ko, &Bs[p][laofs0]);
    GLOAD(gb1 + ko, &Bs[p][laofs1]);
  }

  const int slot = (quad ^ ((lrow >> 2) & 3)) * 8;
  int cur = 0;
  int pre = 2;
#define NT2 (ID / 32)
  for (int kt = 0; kt < NT2; ++kt) {
    WAITL0();
    __builtin_amdgcn_s_barrier();
    if (kt + 2 < NT2) {
      const size_t ko = (size_t)(kt + 2) * 32;
      GLOAD(ga0 + ko, &As[pre][laofs0]);
      GLOAD(ga1 + ko, &As[pre][laofs1]);
      GLOAD(gb0 + ko, &Bs[pre][laofs0]);
      GLOAD(gb1 + ko, &Bs[pre][laofs1]);
      WAITV(8);
    } else if (kt + 1 < NT2) {
      WAITV(4);
    } else {
      WAITV(0);
    }
    __builtin_amdgcn_s_barrier();
    __builtin_amdgcn_sched_barrier(0);
    bf16x8 af[4], bfr[4];
#pragma unroll
    for (int i = 0; i < 4; ++i) {
      af[i] = *(const bf16x8*)(&As[cur][(wm * 64 + i * 16 + lrow) * 32 + slot]);
      bfr[i] = *(const bf16x8*)(&Bs[cur][(wn * 64 + i * 16 + lrow) * 32 + slot]);
    }
    __builtin_amdgcn_s_setprio(1);
#pragma unroll
    for (int mt = 0; mt < 4; ++mt)
#pragma unroll
      for (int nt = 0; nt < 4; ++nt)
        acc[mt][nt] =
            __builtin_amdgcn_mfma_f32_16x16x32_bf16(bfr[nt], af[mt], acc[mt][nt], 0, 0, 0);
    __builtin_amdgcn_s_setprio(0);
    cur = (cur == 2) ? 0 : cur + 1;
    pre = (pre == 2) ? 0 : pre + 1;
  }

#pragma unroll
  for (int mt = 0; mt < 4; ++mt) {
    const int gm = m_base + wm * 64 + mt * 16 + lrow;
    if (gm < n_e) {
      bf16_t* orow = y + (size_t)(off + gm) * HD;
#pragma unroll
      for (int nt = 0; nt < 4; ++nt) {
        const int gi0 = n_base + wn * 64 + nt * 16 + quad * 4;
        const float4 bb = *(const float4*)(b2 + e * HD + gi0);
        const float bv[4] = {bb.x, bb.y, bb.z, bb.w};
        bf16_t o[4];
#pragma unroll
        for (int r = 0; r < 4; ++r) o[r] = (bf16_t)(acc[mt][nt][r] + bv[r]);
        *(uint2*)(orow + gi0) = *(uint2*)o;
      }
    }
  }
}

// ---------------- combine: out[t] = w1*y[p1] + w2*y[p2] ----
__global__ __launch_bounds__(256) void combine_kernel(const bf16_t* __restrict__ y,
                                                      const int* __restrict__ pos_of,
                                                      const float* __restrict__ tok_w,
                                                      float* __restrict__ out) {
  const int gid = blockIdx.x * 256 + threadIdx.x;
  const int t = gid >> 7;             // 128 8-wide chunks per token row
  const int c8 = (gid & 127) * 8;
  const int p1 = pos_of[2 * t];
  const int p2 = pos_of[2 * t + 1];
  const float w1 = tok_w[2 * t];
  const float w2 = tok_w[2 * t + 1];
  const bf16x8 a = *(const bf16x8*)(y + (size_t)p1 * HD + c8);
  const bf16x8 b = *(const bf16x8*)(y + (size_t)p2 * HD + c8);
  float* op = out + (size_t)t * HD + c8;
  float ov[8];
#pragma unroll
  for (int j = 0; j < 8; ++j) ov[j] = w1 * (float)a[j] + w2 * (float)b[j];
  *(float4*)op = make_float4(ov[0], ov[1], ov[2], ov[3]);
  *(float4*)(op + 4) = make_float4(ov[4], ov[5], ov[6], ov[7]);
}

extern "C" void kernel_launch(void* const* d_in, const int* in_sizes, int n_in,
                              void* d_out, int out_size, void* d_ws, size_t ws_size,
                              hipStream_t stream) {
  const float* x = (const float*)d_in[0];
  const float* Wg = (const float*)d_in[1];
  const float* W1 = (const float*)d_in[2];
  const float* b1 = (const float*)d_in[3];
  const float* W2 = (const float*)d_in[4];
  const float* b2 = (const float*)d_in[5];
  float* out = (float*)d_out;
  char* ws = (char*)d_ws;

  int* counts = (int*)(ws + WS_COUNTS);
  int* offsets = (int*)(ws + WS_OFFSETS);
  int* bucket_tok = (int*)(ws + WS_BTOK);
  float* bucket_w = (float*)(ws + WS_BW);
  int* tok_e = (int*)(ws + WS_TE);
  float* tok_w = (float*)(ws + WS_TW);
  int* wl_e = (int*)(ws + WS_WL);
  int* wl_m = wl_e + MAXWL;
  int* n_work = wl_m + MAXWL;
  int* pos_of = (int*)(ws + WS_POS);
  int* rank_of = (int*)(ws + WS_RANK);
  int* blk_cnt = (int*)(ws + WS_BLKC);
  int* blk_base = (int*)(ws + WS_BLKB);
  bf16_t* xb = (bf16_t*)(ws + WS_XB);
  bf16_t* h1 = (bf16_t*)(ws + WS_H1);
  bf16_t* WT = (bf16_t*)(ws + WS_WT);
  bf16_t* y = (bf16_t*)(ws + WS_Y);

  gate_kernel<<<GB, 256, 0, stream>>>(x, Wg, xb, tok_e, tok_w, rank_of, blk_cnt);
  scan_kernel<<<1, 64, 0, stream>>>(blk_cnt, counts, offsets, blk_base, wl_e, wl_m, n_work);
  scatter_kernel<<<TOKS * 2 / 256, 256, 0, stream>>>(tok_e, tok_w, blk_base, rank_of,
                                                     bucket_tok, bucket_w, pos_of);
  transpose_convert_kernel<<<dim3(HD / 64, ID / 64, NE), 256, 0, stream>>>(W1, WT, HD, ID);
  gemm1_kernel<<<dim3(MAXWL, ID / 128), 256, 0, stream>>>(xb, WT, b1, counts, offsets, bucket_tok,
                                                          wl_e, wl_m, n_work, h1);
  transpose_convert_kernel<<<dim3(ID / 64, HD / 64, NE), 256, 0, stream>>>(W2, WT, ID, HD);
  gemm2_kernel<<<dim3(MAXWL, HD / 128), 256, 0, stream>>>(h1, WT, b2, counts, offsets, wl_e,
                                                          wl_m, n_work, y);
  combine_kernel<<<TOKS * HD / (256 * 8), 256, 0, stream>>>(y, pos_of, tok_w, out);
}